// Round 1
// baseline (7680.780 us; speedup 1.0000x reference)
//
#include <hip/hip_runtime.h>
#include <math.h>

// ---------------- problem constants ----------------
#define NTOK  65536
#define EDIM  128
#define HN    4
#define DHD   32
#define MF    256
#define LLAYERS 2
#define INDIM 512
#define FDIM  512     // 4*E
#define NCH   64      // row-chunks per head for attention kernels

#define DN    0.4204482076268573f     // 32^-0.25
#define DN2   0.17677669529663687f    // 32^-0.5
#define RATIO 0.0625f                 // 256^-0.5
#define KEPS  1e-4f

// Workspace layout (floats): 5 * N*E + N*512 + attention scratch ~= 311 MB.

// ---- ordered-uint float max encoding (deterministic global atomic max) ----
__device__ __forceinline__ unsigned f2ord(float f){
  unsigned u = __float_as_uint(f);
  return (u & 0x80000000u) ? ~u : (u | 0x80000000u);
}
__device__ __forceinline__ float ord2f(unsigned e){
  unsigned u = (e & 0x80000000u) ? (e & 0x7fffffffu) : ~e;
  return __uint_as_float(u);
}

// ---------------- generic GEMM: C[n,j] = op(A[n,:]@B[:,j] + bias[j]) + res[n,j] ----------------
// A: [NTOK,K], B: [K,J] row-major, C/res: [NTOK,J]. op: 0=none, 1=exact GELU, 2=ReLU.
// grid: (NTOK/32, J/128), block 256.
__global__ __launch_bounds__(256) void gemm_kernel(
    const float* __restrict__ A, const float* __restrict__ B,
    const float* __restrict__ bias, const float* __restrict__ res,
    float* __restrict__ C, int K, int J, int op)
{
  __shared__ float As[32][32];
  __shared__ float Bs[32][128];
  const int tid = threadIdx.x;
  const int jl  = tid & 127;
  const int rg  = tid >> 7;          // 0/1 -> rows rg*16..rg*16+15
  const int n0  = blockIdx.x * 32;
  const int jbase = blockIdx.y * 128;
  const int jcol  = jbase + jl;

  float acc[16];
#pragma unroll
  for (int r = 0; r < 16; ++r) acc[r] = 0.f;

  for (int k0 = 0; k0 < K; k0 += 32) {
#pragma unroll
    for (int i = 0; i < 4; ++i) {          // A tile: 32x32 scalar, coalesced along k
      int idx = i * 256 + tid;
      int r = idx >> 5, kk = idx & 31;
      As[r][kk] = A[(size_t)(n0 + r) * K + k0 + kk];
    }
#pragma unroll
    for (int i = 0; i < 4; ++i) {          // B tile: 32x128 via float4
      int idx = i * 256 + tid;
      int kk = idx >> 5, j4 = idx & 31;
      float4 bv = *reinterpret_cast<const float4*>(B + (size_t)(k0 + kk) * J + jbase + j4 * 4);
      *reinterpret_cast<float4*>(&Bs[kk][j4 * 4]) = bv;
    }
    __syncthreads();
#pragma unroll
    for (int kk = 0; kk < 32; kk += 4) {
      float4 b0;
      b0.x = Bs[kk + 0][jl]; b0.y = Bs[kk + 1][jl];
      b0.z = Bs[kk + 2][jl]; b0.w = Bs[kk + 3][jl];
#pragma unroll
      for (int r = 0; r < 16; ++r) {
        float4 a = *reinterpret_cast<const float4*>(&As[rg * 16 + r][kk]);
        acc[r] += a.x * b0.x + a.y * b0.y + a.z * b0.z + a.w * b0.w;
      }
    }
    __syncthreads();
  }

  const float bsv = bias ? bias[jcol] : 0.f;
#pragma unroll
  for (int r = 0; r < 16; ++r) {
    int n = n0 + rg * 16 + r;
    float v = acc[r] + bsv;
    if (op == 1)      v = 0.5f * v * (1.f + erff(v * 0.70710678118654752f));
    else if (op == 2) v = fmaxf(v, 0.f);
    if (res) v += res[(size_t)n * J + jcol];
    C[(size_t)n * J + jcol] = v;
  }
}

// ---------------- LayerNorm over E=128: O = LN(X (+R)) * g + b ----------------
// one wave (64 lanes) per row, 4 rows/block. In-place (O==X) is safe.
__global__ __launch_bounds__(256) void ln_kernel(
    const float* __restrict__ X, const float* __restrict__ R,
    const float* __restrict__ g, const float* __restrict__ b,
    float* __restrict__ O)
{
  const int lane = threadIdx.x & 63, wv = threadIdx.x >> 6;
  const int n = blockIdx.x * 4 + wv;
  const size_t base = (size_t)n * EDIM;
  float e0 = X[base + lane], e1 = X[base + lane + 64];
  if (R) { e0 += R[base + lane]; e1 += R[base + lane + 64]; }
  float s = e0 + e1;
#pragma unroll
  for (int o = 1; o < 64; o <<= 1) s += __shfl_xor(s, o);
  float mu = s * (1.f / 128.f);
  float d0 = e0 - mu, d1 = e1 - mu;
  float v = d0 * d0 + d1 * d1;
#pragma unroll
  for (int o = 1; o < 64; o <<= 1) v += __shfl_xor(v, o);
  float rs = rsqrtf(v * (1.f / 128.f) + 1e-5f);
  O[base + lane]      = d0 * rs * g[lane]      + b[lane];
  O[base + lane + 64] = d1 * rs * g[lane + 64] + b[lane + 64];
}

// ---------------- attention: pass 1 -> global max of dd_k (k-stab) ----------------
__global__ void stab_init_kernel(unsigned* p){ *p = 0x007FFFFFu; /* f2ord(-inf) */ }

// grid H*NCH, block 256 (thread = m feature). dd = (k*dn) . proj[m]
__global__ __launch_bounds__(256) void stabmax_kernel(
    const float* __restrict__ Km, const float* __restrict__ projl,
    unsigned* __restrict__ stabp)
{
  __shared__ float Ks[16][32];
  __shared__ float wred[4];
  const int tid = threadIdx.x, lane = tid & 63, wv = tid >> 6;
  const int hh = blockIdx.x / NCH, ch = blockIdx.x % NCH;
  const int n0 = ch * (NTOK / NCH);
  float pj[32];
#pragma unroll
  for (int d = 0; d < 32; ++d) pj[d] = projl[tid * 32 + d] * DN;
  float lm = -3.4e38f;
  for (int t0 = 0; t0 < NTOK / NCH; t0 += 16) {
    __syncthreads();
#pragma unroll
    for (int i = 0; i < 2; ++i) {
      int idx = i * 256 + tid;
      int r = idx >> 5, c = idx & 31;
      Ks[r][c] = Km[(size_t)(n0 + t0 + r) * EDIM + hh * DHD + c];
    }
    __syncthreads();
#pragma unroll 4
    for (int r = 0; r < 16; ++r) {
      float kr[32];
#pragma unroll
      for (int d = 0; d < 32; d += 4) {
        float4 f = *reinterpret_cast<const float4*>(&Ks[r][d]);
        kr[d] = f.x; kr[d + 1] = f.y; kr[d + 2] = f.z; kr[d + 3] = f.w;
      }
      float s = 0.f;
#pragma unroll
      for (int d = 0; d < 32; ++d) s += kr[d] * pj[d];
      lm = fmaxf(lm, s);
    }
  }
#pragma unroll
  for (int o = 1; o < 64; o <<= 1) lm = fmaxf(lm, __shfl_xor(lm, o));
  if (lane == 0) wred[wv] = lm;
  __syncthreads();
  if (tid == 0) {
    float bm = fmaxf(fmaxf(wred[0], wred[1]), fmaxf(wred[2], wred[3]));
    atomicMax(stabp, f2ord(bm));
  }
}

// ---------------- attention: pass 2 -> per-chunk partial ctx[m][d], ksum[m] ----------------
// grid H*NCH, block 256 (thread = m). Deterministic: partials + tree reduce.
__global__ __launch_bounds__(256) void ctx_kernel(
    const float* __restrict__ Km, const float* __restrict__ Vm,
    const float* __restrict__ projl, const unsigned* __restrict__ stabp,
    float* __restrict__ pctx, float* __restrict__ pks)
{
  __shared__ float KV[16][64];   // [row][0:32]=k, [32:64]=v
  const int m = threadIdx.x;
  const int hh = blockIdx.x / NCH, ch = blockIdx.x % NCH;
  const int n0 = ch * (NTOK / NCH);
  float pj[32];
#pragma unroll
  for (int d = 0; d < 32; ++d) pj[d] = projl[m * 32 + d] * DN;
  const float stab = ord2f(*stabp);
  float ctxa[32];
#pragma unroll
  for (int d = 0; d < 32; ++d) ctxa[d] = 0.f;
  float ks = 0.f;

  for (int t0 = 0; t0 < NTOK / NCH; t0 += 16) {
    __syncthreads();
#pragma unroll
    for (int i = 0; i < 4; ++i) {
      int idx = i * 256 + m;
      int r = idx >> 6, c = idx & 63;
      int n = n0 + t0 + r;
      KV[r][c] = (c < 32) ? Km[(size_t)n * EDIM + hh * DHD + c]
                          : Vm[(size_t)n * EDIM + hh * DHD + (c - 32)];
    }
    __syncthreads();
    for (int r = 0; r < 16; ++r) {
      float kr[32];
#pragma unroll
      for (int d = 0; d < 32; d += 4) {
        float4 f = *reinterpret_cast<const float4*>(&KV[r][d]);
        kr[d] = f.x; kr[d + 1] = f.y; kr[d + 2] = f.z; kr[d + 3] = f.w;
      }
      float dd = 0.f, q2 = 0.f;
#pragma unroll
      for (int d = 0; d < 32; ++d) { dd += kr[d] * pj[d]; q2 += kr[d] * kr[d]; }
      float kf = RATIO * (expf(dd - 0.5f * DN2 * q2 - stab) + KEPS);
      ks += kf;
#pragma unroll
      for (int d = 0; d < 32; d += 4) {
        float4 f = *reinterpret_cast<const float4*>(&KV[r][32 + d]);
        ctxa[d] += kf * f.x; ctxa[d + 1] += kf * f.y;
        ctxa[d + 2] += kf * f.z; ctxa[d + 3] += kf * f.w;
      }
    }
  }
  const size_t pb = (size_t)(hh * NCH + ch) * (MF * DHD) + (size_t)m * DHD;
#pragma unroll
  for (int d = 0; d < 32; ++d) pctx[pb + d] = ctxa[d];
  pks[(size_t)(hh * NCH + ch) * MF + m] = ks;
}

__global__ __launch_bounds__(256) void reduce_ctx_kernel(
    const float* __restrict__ p, float* __restrict__ ctx)
{
  int idx = blockIdx.x * 256 + threadIdx.x;     // h*8192 + m*32 + d  (32768 total)
  int hh = idx >> 13, md = idx & 8191;
  float s = 0.f;
  for (int c = 0; c < NCH; ++c) s += p[(size_t)(hh * NCH + c) * (MF * DHD) + md];
  ctx[idx] = s;
}

__global__ __launch_bounds__(256) void reduce_ksum_kernel(
    const float* __restrict__ p, float* __restrict__ ks)
{
  int idx = blockIdx.x * 256 + threadIdx.x;     // h*256 + m  (1024 total)
  int hh = idx >> 8, m = idx & 255;
  float s = 0.f;
  for (int c = 0; c < NCH; ++c) s += p[(size_t)(hh * NCH + c) * MF + m];
  ks[idx] = s;
}

// ---------------- attention: pass 3 -> qf, D, output a[n, h*32+d] ----------------
// grid H*NCH, block 256. Per 8-row tile: phase1 (thread=m) qf + row-max + D;
// phase2 (thread=(g,d)) qf@ctx with ctx column register-cached.
__global__ __launch_bounds__(256) void attn_out_kernel(
    const float* __restrict__ Qm, const float* __restrict__ projl,
    const float* __restrict__ ctxg, const float* __restrict__ ksg,
    float* __restrict__ Am)
{
  __shared__ float qs[8][32];
  __shared__ float qfs[8][256];
  __shared__ float wmax[4][8];
  __shared__ float wsum[4][8];
  __shared__ float ored[8][264];   // [r][g*33+d], padded stride 33
  const int tid = threadIdx.x, lane = tid & 63, wv = tid >> 6;
  const int hh = blockIdx.x / NCH, ch = blockIdx.x % NCH;
  const int n0 = ch * (NTOK / NCH);
  const int g = tid >> 5, d2 = tid & 31;

  float pj[32];
#pragma unroll
  for (int d = 0; d < 32; ++d) pj[d] = projl[tid * 32 + d] * DN;
  const float ksv = ksg[hh * MF + tid];
  float creg[32];                               // ctx[h][g*32+mm][d2]
#pragma unroll
  for (int mm = 0; mm < 32; ++mm)
    creg[mm] = ctxg[hh * MF * DHD + (g * 32 + mm) * DHD + d2];

  for (int t0 = 0; t0 < NTOK / NCH; t0 += 8) {
    __syncthreads();
    { int r = tid >> 5, c = tid & 31;
      qs[r][c] = Qm[(size_t)(n0 + t0 + r) * EDIM + hh * DHD + c]; }
    __syncthreads();

    float dd[8], dg[8];
#pragma unroll
    for (int rr = 0; rr < 8; ++rr) {
      float qr[32];
#pragma unroll
      for (int d = 0; d < 32; d += 4) {
        float4 f = *reinterpret_cast<const float4*>(&qs[rr][d]);
        qr[d] = f.x; qr[d + 1] = f.y; qr[d + 2] = f.z; qr[d + 3] = f.w;
      }
      float s = 0.f, q2 = 0.f;
#pragma unroll
      for (int d = 0; d < 32; ++d) { s += qr[d] * pj[d]; q2 += qr[d] * qr[d]; }
      dd[rr] = s; dg[rr] = 0.5f * DN2 * q2;
    }
#pragma unroll
    for (int rr = 0; rr < 8; ++rr) {
      float v = dd[rr];
#pragma unroll
      for (int o = 1; o < 64; o <<= 1) v = fmaxf(v, __shfl_xor(v, o));
      if (lane == 0) wmax[wv][rr] = v;
    }
    __syncthreads();
#pragma unroll
    for (int rr = 0; rr < 8; ++rr) {
      float st = fmaxf(fmaxf(wmax[0][rr], wmax[1][rr]), fmaxf(wmax[2][rr], wmax[3][rr]));
      float qv = RATIO * (expf(dd[rr] - dg[rr] - st) + KEPS);
      qfs[rr][tid] = qv;
      float dp = qv * ksv;
#pragma unroll
      for (int o = 1; o < 64; o <<= 1) dp += __shfl_xor(dp, o);
      if (lane == 0) wsum[wv][rr] = dp;
    }
    __syncthreads();
    float pr[8];
#pragma unroll
    for (int rr = 0; rr < 8; ++rr) {
      float s = 0.f;
#pragma unroll
      for (int mm = 0; mm < 32; ++mm) s += qfs[rr][g * 32 + mm] * creg[mm];
      pr[rr] = s;
    }
#pragma unroll
    for (int rr = 0; rr < 8; ++rr) ored[rr][g * 33 + d2] = pr[rr];
    __syncthreads();
    { int rr = tid >> 5, d = tid & 31;
      float s = 0.f;
#pragma unroll
      for (int g2 = 0; g2 < 8; ++g2) s += ored[rr][g2 * 33 + d];
      float Dv = wsum[0][rr] + wsum[1][rr] + wsum[2][rr] + wsum[3][rr];
      Am[(size_t)(n0 + t0 + rr) * EDIM + hh * DHD + d] = s / Dv; }
  }
}

// ---------------- classifier: out[n] = sigmoid(h[n,:]@Wc + bc) ----------------
__global__ __launch_bounds__(256) void cls_kernel(
    const float* __restrict__ Hm, const float* __restrict__ Wc,
    const float* __restrict__ bc, float* __restrict__ out)
{
  const int lane = threadIdx.x & 63, wv = threadIdx.x >> 6;
  const int n = blockIdx.x * 4 + wv;
  const size_t base = (size_t)n * EDIM;
  float s = Hm[base + lane] * Wc[lane] + Hm[base + lane + 64] * Wc[lane + 64];
#pragma unroll
  for (int o = 1; o < 64; o <<= 1) s += __shfl_xor(s, o);
  if (lane == 0) out[n] = 1.f / (1.f + expf(-(s + bc[0])));
}

// ---------------- host ----------------
extern "C" void kernel_launch(void* const* d_in, const int* in_sizes, int n_in,
                              void* d_out, int out_size, void* d_ws, size_t ws_size,
                              hipStream_t stream)
{
  const float* x    = (const float*)d_in[0];
  const float* Wpin = (const float*)d_in[1];
  const float* bpin = (const float*)d_in[2];
  const float* lag  = (const float*)d_in[3];
  const float* lab  = (const float*)d_in[4];
  const float* Wq   = (const float*)d_in[5];
  const float* Wk   = (const float*)d_in[6];
  const float* Wv   = (const float*)d_in[7];
  const float* Wo   = (const float*)d_in[8];
  const float* bo   = (const float*)d_in[9];
  const float* lbg  = (const float*)d_in[10];
  const float* lbb  = (const float*)d_in[11];
  const float* Wf1  = (const float*)d_in[12];
  const float* bf1  = (const float*)d_in[13];
  const float* Wf2  = (const float*)d_in[14];
  const float* bf2  = (const float*)d_in[15];
  const float* Wpo  = (const float*)d_in[16];
  const float* bpo  = (const float*)d_in[17];
  const float* n1g  = (const float*)d_in[18];
  const float* n1b  = (const float*)d_in[19];
  const float* Wn1  = (const float*)d_in[20];
  const float* bn1  = (const float*)d_in[21];
  const float* Wn2  = (const float*)d_in[22];
  const float* bn2  = (const float*)d_in[23];
  const float* n2g  = (const float*)d_in[24];
  const float* n2b  = (const float*)d_in[25];
  const float* Wc   = (const float*)d_in[26];
  const float* bc   = (const float*)d_in[27];
  const float* proj = (const float*)d_in[28];

  float* ws = (float*)d_ws;
  const size_t NE = (size_t)NTOK * EDIM;
  float* hbuf = ws;
  float* Ybuf = ws + NE;
  float* Qbuf = ws + 2 * NE;
  float* Kbuf = ws + 3 * NE;
  float* Vbuf = ws + 4 * NE;
  float* HIDb = ws + 5 * NE;                         // NTOK*512
  float* ctxb = HIDb + (size_t)NTOK * FDIM;          // H*M*DH
  float* ksb  = ctxb + (size_t)HN * MF * DHD;        // H*M
  float* pctx = ksb + (size_t)HN * MF;               // H*NCH*M*DH
  float* pks  = pctx + (size_t)HN * NCH * MF * DHD;  // H*NCH*M
  unsigned* stabp = (unsigned*)(pks + (size_t)HN * NCH * MF);

  auto gemm = [&](const float* A, const float* B, const float* bias,
                  const float* res, float* C, int K, int J, int op) {
    dim3 grid(NTOK / 32, J / 128);
    gemm_kernel<<<grid, 256, 0, stream>>>(A, B, bias, res, C, K, J, op);
  };

  // input projection: h = x @ Wpin + bpin
  gemm(x, Wpin, bpin, nullptr, hbuf, INDIM, EDIM, 0);

  for (int l = 0; l < LLAYERS; ++l) {
    const float* Wq_l = Wq + (size_t)l * EDIM * EDIM;
    const float* Wk_l = Wk + (size_t)l * EDIM * EDIM;
    const float* Wv_l = Wv + (size_t)l * EDIM * EDIM;
    const float* Wo_l = Wo + (size_t)l * EDIM * EDIM;
    const float* Wpo_l = Wpo + (size_t)l * EDIM * EDIM;
    const float* Wf1_l = Wf1 + (size_t)l * EDIM * FDIM;
    const float* Wf2_l = Wf2 + (size_t)l * FDIM * EDIM;
    const float* Wn1_l = Wn1 + (size_t)l * EDIM * FDIM;
    const float* Wn2_l = Wn2 + (size_t)l * FDIM * EDIM;
    const float* proj_l = proj + (size_t)l * MF * DHD;

    // y = LN(h)
    ln_kernel<<<NTOK / 4, 256, 0, stream>>>(hbuf, nullptr, lag + l * EDIM, lab + l * EDIM, Ybuf);
    // q,k,v
    gemm(Ybuf, Wq_l, nullptr, nullptr, Qbuf, EDIM, EDIM, 0);
    gemm(Ybuf, Wk_l, nullptr, nullptr, Kbuf, EDIM, EDIM, 0);
    gemm(Ybuf, Wv_l, nullptr, nullptr, Vbuf, EDIM, EDIM, 0);
    // FAVOR+
    stab_init_kernel<<<1, 1, 0, stream>>>(stabp);
    stabmax_kernel<<<HN * NCH, 256, 0, stream>>>(Kbuf, proj_l, stabp);
    ctx_kernel<<<HN * NCH, 256, 0, stream>>>(Kbuf, Vbuf, proj_l, stabp, pctx, pks);
    reduce_ctx_kernel<<<HN * MF * DHD / 256, 256, 0, stream>>>(pctx, ctxb);
    reduce_ksum_kernel<<<HN * MF / 256, 256, 0, stream>>>(pks, ksb);
    attn_out_kernel<<<HN * NCH, 256, 0, stream>>>(Qbuf, proj_l, ctxb, ksb, Ybuf); // a -> Ybuf
    // h1 = h + a @ Wo + bo   (-> Qbuf)
    gemm(Ybuf, Wo_l, bo + l * EDIM, hbuf, Qbuf, EDIM, EDIM, 0);
    // y2 = LN(h1) -> Kbuf
    ln_kernel<<<NTOK / 4, 256, 0, stream>>>(Qbuf, nullptr, lbg + l * EDIM, lbb + l * EDIM, Kbuf);
    // h2 = h1 + gelu(y2@Wf1+bf1)@Wf2 + bf2   (-> Vbuf)
    gemm(Kbuf, Wf1_l, bf1 + l * FDIM, nullptr, HIDb, EDIM, FDIM, 1);
    gemm(HIDb, Wf2_l, bf2 + l * EDIM, Qbuf, Vbuf, FDIM, EDIM, 0);
    // attn_out = h2 @ Wpo + bpo -> Ybuf ; h = LN(h + attn_out)
    gemm(Vbuf, Wpo_l, bpo + l * EDIM, nullptr, Ybuf, EDIM, EDIM, 0);
    ln_kernel<<<NTOK / 4, 256, 0, stream>>>(hbuf, Ybuf, n1g + l * EDIM, n1b + l * EDIM, hbuf);
    // ffn = relu(h@Wn1+bn1)@Wn2+bn2 -> Ybuf ; h = LN(h + ffn)
    gemm(hbuf, Wn1_l, bn1 + l * FDIM, nullptr, HIDb, EDIM, FDIM, 2);
    gemm(HIDb, Wn2_l, bn2 + l * EDIM, nullptr, Ybuf, FDIM, EDIM, 0);
    ln_kernel<<<NTOK / 4, 256, 0, stream>>>(hbuf, Ybuf, n2g + l * EDIM, n2b + l * EDIM, hbuf);
  }

  cls_kernel<<<NTOK / 4, 256, 0, stream>>>(hbuf, Wc, bc, (float*)d_out);
}

// Round 2
// 3335.646 us; speedup vs baseline: 2.3026x; 2.3026x over previous
//
#include <hip/hip_runtime.h>
#include <math.h>

// ---------------- problem constants ----------------
#define NTOK  65536
#define EDIM  128
#define HN    4
#define DHD   32
#define MF    256
#define LLAYERS 2
#define INDIM 512
#define FDIM  512
#define ACH   256            // attention row-chunks per head (grid = HN*ACH = 1024)
#define CROWS (NTOK/ACH)     // 256 rows per chunk

#define DN    0.4204482076268573f     // 32^-0.25
#define DN2   0.17677669529663687f    // 32^-0.5
#define RATIO 0.0625f                 // 256^-0.5
#define KEPS  1e-4f

typedef unsigned short u16;
typedef unsigned int   u32;
typedef __attribute__((ext_vector_type(8))) __bf16 bf16x8;
typedef __attribute__((ext_vector_type(4))) float  f32x4;

__device__ __forceinline__ u16 f2bf(float f){
  u32 u = __float_as_uint(f);
  u32 r = (u + 0x7fffu + ((u >> 16) & 1u)) >> 16;   // RNE
  return (u16)r;
}
__device__ __forceinline__ float bf2f(u16 h){ return __uint_as_float(((u32)h) << 16); }

__device__ __forceinline__ void gload_lds16(const void* g, void* l){
  __builtin_amdgcn_global_load_lds(
      (const __attribute__((address_space(1))) u32*)g,
      (__attribute__((address_space(3))) u32*)l, 16, 0, 0);
}

// ---- ordered-uint float max encoding (deterministic global atomic max) ----
__device__ __forceinline__ unsigned f2ord(float f){
  unsigned u = __float_as_uint(f);
  return (u & 0x80000000u) ? ~u : (u | 0x80000000u);
}
__device__ __forceinline__ float ord2f(unsigned e){
  unsigned u = (e & 0x80000000u) ? (e & 0x7fffffffu) : ~e;
  return __uint_as_float(u);
}

// ---------------- fp32 -> bf16 bulk convert (x) ----------------
__global__ __launch_bounds__(256) void cvt_bf16_4(const float4* __restrict__ src,
                                                  ushort4* __restrict__ dst){
  size_t i = (size_t)blockIdx.x * 256 + threadIdx.x;
  float4 f = src[i];
  ushort4 o;
  o.x = f2bf(f.x); o.y = f2bf(f.y); o.z = f2bf(f.z); o.w = f2bf(f.w);
  dst[i] = o;
}

// ---------------- weight transpose+convert: dst[j*K+k] = bf16(src[k*J+j]) ----------------
__global__ __launch_bounds__(256) void tpose_kernel(const float* __restrict__ src,
                                                    u16* __restrict__ dst, int K, int J){
  int idx = blockIdx.x * 256 + threadIdx.x;
  int j = idx / K, k = idx - j * K;
  dst[idx] = f2bf(src[(size_t)k * J + j]);
}

// ---------------- bf16 MFMA GEMM: C = op(A@B + bias) (+res), bf16 out ----------------
// A: [NTOK,K] bf16 row-major; Bt: [J,K] bf16 (B transposed); C/res: [NTOK,J] bf16.
// op: 0 none, 1 exact GELU, 2 ReLU. Tile 128x128, BK=32, 4 waves (2x2 of 64x64).
__global__ __launch_bounds__(256) void gemm_bf16(
    const u16* __restrict__ A, const u16* __restrict__ Bt,
    const float* __restrict__ bias, const u16* __restrict__ res,
    u16* __restrict__ C, int K, int J, int op)
{
  __shared__ u16 Al[128 * 32];
  __shared__ u16 Bl[128 * 32];
  const int tid  = threadIdx.x;
  const int lane = tid & 63;
  const int w    = tid >> 6;
  const int wr   = w >> 1, wc = w & 1;
  const int n0   = blockIdx.x * 128;
  const int jb   = blockIdx.y * 128;

  f32x4 acc[4][4];
#pragma unroll
  for (int m = 0; m < 4; ++m)
#pragma unroll
    for (int n = 0; n < 4; ++n) acc[m][n] = (f32x4){0.f, 0.f, 0.f, 0.f};

  // staging: wave w stages segments (w*2+c), c=0,1: 16 rows x 64B each
  const int srow = lane >> 2;           // 0..15
  const int scol = (lane & 3) * 8;      // ushort offset in row
  const u16* ga0 = A  + (size_t)(n0 + (w * 2 + 0) * 16 + srow) * K + scol;
  const u16* ga1 = A  + (size_t)(n0 + (w * 2 + 1) * 16 + srow) * K + scol;
  const u16* gb0 = Bt + (size_t)(jb + (w * 2 + 0) * 16 + srow) * K + scol;
  const u16* gb1 = Bt + (size_t)(jb + (w * 2 + 1) * 16 + srow) * K + scol;
  u16* la0 = &Al[(w * 2 + 0) * 512];
  u16* la1 = &Al[(w * 2 + 1) * 512];
  u16* lb0 = &Bl[(w * 2 + 0) * 512];
  u16* lb1 = &Bl[(w * 2 + 1) * 512];

  // fragment LDS indices (constant over K loop)
  int aidx[4], bidx[4];
#pragma unroll
  for (int m = 0; m < 4; ++m) aidx[m] = (wr * 64 + m * 16 + (lane & 15)) * 32 + (lane >> 4) * 8;
#pragma unroll
  for (int n = 0; n < 4; ++n) bidx[n] = (wc * 64 + n * 16 + (lane & 15)) * 32 + (lane >> 4) * 8;

  for (int k0 = 0; k0 < K; k0 += 32) {
    __syncthreads();                      // prior compute done before overwrite
    gload_lds16(ga0 + k0, la0);
    gload_lds16(ga1 + k0, la1);
    gload_lds16(gb0 + k0, lb0);
    gload_lds16(gb1 + k0, lb1);
    __syncthreads();                      // drains vmcnt -> LDS tiles ready
    bf16x8 af[4], bfg[4];
#pragma unroll
    for (int m = 0; m < 4; ++m) af[m]  = *reinterpret_cast<const bf16x8*>(&Al[aidx[m]]);
#pragma unroll
    for (int n = 0; n < 4; ++n) bfg[n] = *reinterpret_cast<const bf16x8*>(&Bl[bidx[n]]);
#pragma unroll
    for (int m = 0; m < 4; ++m)
#pragma unroll
      for (int n = 0; n < 4; ++n)
        acc[m][n] = __builtin_amdgcn_mfma_f32_16x16x32_bf16(af[m], bfg[n], acc[m][n], 0, 0, 0);
  }

  // epilogue: C/D layout col=lane&15, row=(lane>>4)*4+j  [m89-verified]
  const int col0 = jb + wc * 64 + (lane & 15);
  const int row0 = n0 + wr * 64 + (lane >> 4) * 4;
  float bv[4];
#pragma unroll
  for (int n = 0; n < 4; ++n) bv[n] = bias ? bias[col0 + n * 16] : 0.f;
#pragma unroll
  for (int m = 0; m < 4; ++m) {
#pragma unroll
    for (int n = 0; n < 4; ++n) {
      const int gcol = col0 + n * 16;
#pragma unroll
      for (int j = 0; j < 4; ++j) {
        const int grow = row0 + m * 16 + j;
        float v = acc[m][n][j] + bv[n];
        if (op == 1)      v = 0.5f * v * (1.f + erff(v * 0.70710678118654752f));
        else if (op == 2) v = fmaxf(v, 0.f);
        if (res) v += bf2f(res[(size_t)grow * J + gcol]);
        C[(size_t)grow * J + gcol] = f2bf(v);
      }
    }
  }
}

// ---------------- LayerNorm over E=128 (bf16 io): O = LN(X (+R)) * g + b ----------------
__global__ __launch_bounds__(256) void ln_bf16(
    const u16* __restrict__ X, const u16* __restrict__ R,
    const float* __restrict__ g, const float* __restrict__ b,
    u16* __restrict__ O)
{
  const int lane = threadIdx.x & 63, wv = threadIdx.x >> 6;
  const int n = blockIdx.x * 4 + wv;
  const size_t ub = (size_t)n * 64 + lane;
  u32 u = ((const u32*)X)[ub];
  float e0 = bf2f((u16)(u & 0xffff)), e1 = bf2f((u16)(u >> 16));
  if (R) {
    u32 ru = ((const u32*)R)[ub];
    e0 += bf2f((u16)(ru & 0xffff)); e1 += bf2f((u16)(ru >> 16));
  }
  float s = e0 + e1;
#pragma unroll
  for (int o = 1; o < 64; o <<= 1) s += __shfl_xor(s, o);
  float mu = s * (1.f / 128.f);
  float d0 = e0 - mu, d1 = e1 - mu;
  float v = d0 * d0 + d1 * d1;
#pragma unroll
  for (int o = 1; o < 64; o <<= 1) v += __shfl_xor(v, o);
  float rs = rsqrtf(v * (1.f / 128.f) + 1e-5f);
  float o0 = d0 * rs * g[2 * lane]     + b[2 * lane];
  float o1 = d1 * rs * g[2 * lane + 1] + b[2 * lane + 1];
  ((u32*)O)[ub] = (u32)f2bf(o0) | ((u32)f2bf(o1) << 16);
}

// ---------------- attention pass 1: global max of dd_k ----------------
__global__ void stab_init_kernel(unsigned* p){ *p = 0x007FFFFFu; /* f2ord(-inf) */ }

__global__ __launch_bounds__(256) void stabmax_kernel(
    const u16* __restrict__ Km, const float* __restrict__ projl,
    unsigned* __restrict__ stabp)
{
  __shared__ float Ks[16][32];
  __shared__ float wred[4];
  const int tid = threadIdx.x, lane = tid & 63, wv = tid >> 6;
  const int hh = blockIdx.x / ACH, ch = blockIdx.x % ACH;
  const int n0 = ch * CROWS;
  float pj[32];
#pragma unroll
  for (int d = 0; d < 32; ++d) pj[d] = projl[tid * 32 + d] * DN;
  float lm = -3.4e38f;
  for (int t0 = 0; t0 < CROWS; t0 += 16) {
    __syncthreads();
    { int r = tid >> 4, c2 = (tid & 15) * 2;
      u32 u = *(const u32*)&Km[(size_t)(n0 + t0 + r) * EDIM + hh * DHD + c2];
      Ks[r][c2] = bf2f((u16)(u & 0xffff)); Ks[r][c2 + 1] = bf2f((u16)(u >> 16)); }
    __syncthreads();
#pragma unroll 4
    for (int r = 0; r < 16; ++r) {
      float s = 0.f;
#pragma unroll
      for (int d = 0; d < 32; ++d) s += Ks[r][d] * pj[d];
      lm = fmaxf(lm, s);
    }
  }
#pragma unroll
  for (int o = 1; o < 64; o <<= 1) lm = fmaxf(lm, __shfl_xor(lm, o));
  if (lane == 0) wred[wv] = lm;
  __syncthreads();
  if (tid == 0) {
    float bm = fmaxf(fmaxf(wred[0], wred[1]), fmaxf(wred[2], wred[3]));
    atomicMax(stabp, f2ord(bm));
  }
}

// ---------------- attention pass 2: partial ctx[m][d], ksum[m] per chunk ----------------
__global__ __launch_bounds__(256) void ctx_kernel(
    const u16* __restrict__ Km, const u16* __restrict__ Vm,
    const float* __restrict__ projl, const unsigned* __restrict__ stabp,
    float* __restrict__ pctx, float* __restrict__ pks)
{
  __shared__ float KV[16][64];   // [row][0:32]=k, [32:64]=v
  const int m = threadIdx.x;
  const int hh = blockIdx.x / ACH, ch = blockIdx.x % ACH;
  const int n0 = ch * CROWS;
  float pj[32];
#pragma unroll
  for (int d = 0; d < 32; ++d) pj[d] = projl[m * 32 + d] * DN;
  const float stab = ord2f(*stabp);
  float ctxa[32];
#pragma unroll
  for (int d = 0; d < 32; ++d) ctxa[d] = 0.f;
  float ks = 0.f;

  for (int t0 = 0; t0 < CROWS; t0 += 16) {
    __syncthreads();
#pragma unroll
    for (int i = 0; i < 2; ++i) {
      int idx = i * 256 + m;
      int r = idx >> 5, c2 = (idx & 31) * 2;
      int n = n0 + t0 + r;
      u32 u = (c2 < 32) ? *(const u32*)&Km[(size_t)n * EDIM + hh * DHD + c2]
                        : *(const u32*)&Vm[(size_t)n * EDIM + hh * DHD + (c2 - 32)];
      KV[r][c2] = bf2f((u16)(u & 0xffff)); KV[r][c2 + 1] = bf2f((u16)(u >> 16));
    }
    __syncthreads();
    for (int r = 0; r < 16; ++r) {
      float dd = 0.f, q2 = 0.f;
#pragma unroll
      for (int d = 0; d < 32; ++d) { float kv = KV[r][d]; dd += kv * pj[d]; q2 += kv * kv; }
      float kf = RATIO * (expf(dd - 0.5f * DN2 * q2 - stab) + KEPS);
      ks += kf;
#pragma unroll
      for (int d = 0; d < 32; ++d) ctxa[d] += kf * KV[r][32 + d];
    }
  }
  const size_t pb = (size_t)(hh * ACH + ch) * (MF * DHD) + (size_t)m * DHD;
#pragma unroll
  for (int d = 0; d < 32; ++d) pctx[pb + d] = ctxa[d];
  pks[(size_t)(hh * ACH + ch) * MF + m] = ks;
}

__global__ __launch_bounds__(256) void reduce_ctx_kernel(
    const float* __restrict__ p, float* __restrict__ ctx)
{
  int idx = blockIdx.x * 256 + threadIdx.x;     // h*8192 + m*32 + d (32768)
  int hh = idx >> 13, md = idx & 8191;
  float s = 0.f;
  for (int c = 0; c < ACH; ++c) s += p[(size_t)(hh * ACH + c) * (MF * DHD) + md];
  ctx[idx] = s;
}

__global__ __launch_bounds__(256) void reduce_ksum_kernel(
    const float* __restrict__ p, float* __restrict__ ks)
{
  int idx = blockIdx.x * 256 + threadIdx.x;     // h*256 + m (1024)
  int hh = idx >> 8, m = idx & 255;
  float s = 0.f;
  for (int c = 0; c < ACH; ++c) s += p[(size_t)(hh * ACH + c) * MF + m];
  ks[idx] = s;
}

// ---------------- attention pass 3: qf, D, out ----------------
__global__ __launch_bounds__(256) void attn_out_kernel(
    const u16* __restrict__ Qm, const float* __restrict__ projl,
    const float* __restrict__ ctxg, const float* __restrict__ ksg,
    u16* __restrict__ Am)
{
  __shared__ float qs[8][32];
  __shared__ float qfs[8][256];
  __shared__ float wmax[4][8];
  __shared__ float wsum[4][8];
  __shared__ float ored[8][264];
  const int tid = threadIdx.x, lane = tid & 63, wv = tid >> 6;
  const int hh = blockIdx.x / ACH, ch = blockIdx.x % ACH;
  const int n0 = ch * CROWS;
  const int g = tid >> 5, d2 = tid & 31;

  float pj[32];
#pragma unroll
  for (int d = 0; d < 32; ++d) pj[d] = projl[tid * 32 + d] * DN;
  const float ksv = ksg[hh * MF + tid];
  float creg[32];
#pragma unroll
  for (int mm = 0; mm < 32; ++mm)
    creg[mm] = ctxg[hh * MF * DHD + (g * 32 + mm) * DHD + d2];

  for (int t0 = 0; t0 < CROWS; t0 += 8) {
    __syncthreads();
    { int r = tid >> 5, c = tid & 31;
      qs[r][c] = bf2f(Qm[(size_t)(n0 + t0 + r) * EDIM + hh * DHD + c]); }
    __syncthreads();

    float dd[8], dg[8];
#pragma unroll
    for (int rr = 0; rr < 8; ++rr) {
      float s = 0.f, q2 = 0.f;
#pragma unroll
      for (int d = 0; d < 32; ++d) { float qv = qs[rr][d]; s += qv * pj[d]; q2 += qv * qv; }
      dd[rr] = s; dg[rr] = 0.5f * DN2 * q2;
    }
#pragma unroll
    for (int rr = 0; rr < 8; ++rr) {
      float v = dd[rr];
#pragma unroll
      for (int o = 1; o < 64; o <<= 1) v = fmaxf(v, __shfl_xor(v, o));
      if (lane == 0) wmax[wv][rr] = v;
    }
    __syncthreads();
#pragma unroll
    for (int rr = 0; rr < 8; ++rr) {
      float st = fmaxf(fmaxf(wmax[0][rr], wmax[1][rr]), fmaxf(wmax[2][rr], wmax[3][rr]));
      float qv = RATIO * (expf(dd[rr] - dg[rr] - st) + KEPS);
      qfs[rr][tid] = qv;
      float dp = qv * ksv;
#pragma unroll
      for (int o = 1; o < 64; o <<= 1) dp += __shfl_xor(dp, o);
      if (lane == 0) wsum[wv][rr] = dp;
    }
    __syncthreads();
    float pr[8];
#pragma unroll
    for (int rr = 0; rr < 8; ++rr) {
      float s = 0.f;
#pragma unroll
      for (int mm = 0; mm < 32; ++mm) s += qfs[rr][g * 32 + mm] * creg[mm];
      pr[rr] = s;
    }
#pragma unroll
    for (int rr = 0; rr < 8; ++rr) ored[rr][g * 33 + d2] = pr[rr];
    __syncthreads();
    { int rr = tid >> 5, d = tid & 31;
      float s = 0.f;
#pragma unroll
      for (int g2 = 0; g2 < 8; ++g2) s += ored[rr][g2 * 33 + d];
      float Dv = wsum[0][rr] + wsum[1][rr] + wsum[2][rr] + wsum[3][rr];
      Am[(size_t)(n0 + t0 + rr) * EDIM + hh * DHD + d] = f2bf(s / Dv); }
  }
}

// ---------------- classifier ----------------
__global__ __launch_bounds__(256) void cls_kernel(
    const u16* __restrict__ Hm, const float* __restrict__ Wc,
    const float* __restrict__ bc, float* __restrict__ out)
{
  const int lane = threadIdx.x & 63, wv = threadIdx.x >> 6;
  const int n = blockIdx.x * 4 + wv;
  u32 u = ((const u32*)Hm)[(size_t)n * 64 + lane];
  float e0 = bf2f((u16)(u & 0xffff)), e1 = bf2f((u16)(u >> 16));
  float s = e0 * Wc[2 * lane] + e1 * Wc[2 * lane + 1];
#pragma unroll
  for (int o = 1; o < 64; o <<= 1) s += __shfl_xor(s, o);
  if (lane == 0) out[n] = 1.f / (1.f + expf(-(s + bc[0])));
}

// ---------------- host ----------------
extern "C" void kernel_launch(void* const* d_in, const int* in_sizes, int n_in,
                              void* d_out, int out_size, void* d_ws, size_t ws_size,
                              hipStream_t stream)
{
  const float* x    = (const float*)d_in[0];
  const float* Wpin = (const float*)d_in[1];
  const float* bpin = (const float*)d_in[2];
  const float* lag  = (const float*)d_in[3];
  const float* lab  = (const float*)d_in[4];
  const float* Wq   = (const float*)d_in[5];
  const float* Wk   = (const float*)d_in[6];
  const float* Wv   = (const float*)d_in[7];
  const float* Wo   = (const float*)d_in[8];
  const float* bo   = (const float*)d_in[9];
  const float* lbg  = (const float*)d_in[10];
  const float* lbb  = (const float*)d_in[11];
  const float* Wf1  = (const float*)d_in[12];
  const float* bf1  = (const float*)d_in[13];
  const float* Wf2  = (const float*)d_in[14];
  const float* bf2  = (const float*)d_in[15];
  const float* Wpo  = (const float*)d_in[16];
  const float* bpo  = (const float*)d_in[17];
  const float* n1g  = (const float*)d_in[18];
  const float* n1b  = (const float*)d_in[19];
  const float* Wn1  = (const float*)d_in[20];
  const float* bn1  = (const float*)d_in[21];
  const float* Wn2  = (const float*)d_in[22];
  const float* bn2  = (const float*)d_in[23];
  const float* n2g  = (const float*)d_in[24];
  const float* n2b  = (const float*)d_in[25];
  const float* Wc   = (const float*)d_in[26];
  const float* bc   = (const float*)d_in[27];
  const float* proj = (const float*)d_in[28];

  size_t off = 0;
  char* base = (char*)d_ws;
  auto alloc = [&](size_t bytes) -> void* {
    void* p = base + off;
    off += (bytes + 255) & ~(size_t)255;
    return p;
  };
  u16* xbf = (u16*)alloc((size_t)NTOK * INDIM * 2);
  u16* hb  = (u16*)alloc((size_t)NTOK * EDIM * 2);
  u16* yb  = (u16*)alloc((size_t)NTOK * EDIM * 2);
  u16* qb  = (u16*)alloc((size_t)NTOK * EDIM * 2);
  u16* kb  = (u16*)alloc((size_t)NTOK * EDIM * 2);
  u16* vb  = (u16*)alloc((size_t)NTOK * EDIM * 2);
  u16* hid = (u16*)alloc((size_t)NTOK * FDIM * 2);
  float* ctxb = (float*)alloc((size_t)HN * MF * DHD * 4);
  float* ksb  = (float*)alloc((size_t)HN * MF * 4);
  float* pctx = (float*)alloc((size_t)HN * ACH * MF * DHD * 4);
  float* pks  = (float*)alloc((size_t)HN * ACH * MF * 4);
  unsigned* stabp = (unsigned*)alloc(256);
  u16* wts = (u16*)alloc((size_t)753664 * 2);

  // weight sub-offsets
  size_t wo = 0;
  u16* Wpint = wts + wo; wo += 512 * 128;
  u16 *Wqt[LLAYERS], *Wkt[LLAYERS], *Wvt[LLAYERS], *Wot[LLAYERS], *Wpot[LLAYERS];
  u16 *Wf1t[LLAYERS], *Wf2t[LLAYERS], *Wn1t[LLAYERS], *Wn2t[LLAYERS];
  for (int l = 0; l < LLAYERS; ++l) {
    Wqt[l]  = wts + wo; wo += 128 * 128;
    Wkt[l]  = wts + wo; wo += 128 * 128;
    Wvt[l]  = wts + wo; wo += 128 * 128;
    Wot[l]  = wts + wo; wo += 128 * 128;
    Wpot[l] = wts + wo; wo += 128 * 128;
    Wf1t[l] = wts + wo; wo += 128 * 512;
    Wf2t[l] = wts + wo; wo += 512 * 128;
    Wn1t[l] = wts + wo; wo += 128 * 512;
    Wn2t[l] = wts + wo; wo += 512 * 128;
  }

  // convert x -> bf16
  cvt_bf16_4<<<(NTOK * INDIM / 4) / 256, 256, 0, stream>>>(
      (const float4*)x, (ushort4*)xbf);

  // transpose+convert weights
  auto tp = [&](const float* s, u16* d, int K, int J) {
    tpose_kernel<<<(K * J) / 256, 256, 0, stream>>>(s, d, K, J);
  };
  tp(Wpin, Wpint, INDIM, EDIM);
  for (int l = 0; l < LLAYERS; ++l) {
    tp(Wq  + (size_t)l * 16384, Wqt[l],  128, 128);
    tp(Wk  + (size_t)l * 16384, Wkt[l],  128, 128);
    tp(Wv  + (size_t)l * 16384, Wvt[l],  128, 128);
    tp(Wo  + (size_t)l * 16384, Wot[l],  128, 128);
    tp(Wpo + (size_t)l * 16384, Wpot[l], 128, 128);
    tp(Wf1 + (size_t)l * 65536, Wf1t[l], 128, 512);
    tp(Wf2 + (size_t)l * 65536, Wf2t[l], 512, 128);
    tp(Wn1 + (size_t)l * 65536, Wn1t[l], 128, 512);
    tp(Wn2 + (size_t)l * 65536, Wn2t[l], 512, 128);
  }

  auto gemm = [&](const u16* A, const u16* Bt, const float* bias,
                  const u16* res, u16* C, int K, int J, int op) {
    dim3 grid(NTOK / 128, J / 128);
    gemm_bf16<<<grid, 256, 0, stream>>>(A, Bt, bias, res, C, K, J, op);
  };

  // h = x @ Wpin + bpin
  gemm(xbf, Wpint, bpin, nullptr, hb, INDIM, EDIM, 0);

  for (int l = 0; l < LLAYERS; ++l) {
    const float* proj_l = proj + (size_t)l * MF * DHD;

    // y = LN(h)
    ln_bf16<<<NTOK / 4, 256, 0, stream>>>(hb, nullptr, lag + l * EDIM, lab + l * EDIM, yb);
    // q,k,v
    gemm(yb, Wqt[l], nullptr, nullptr, qb, EDIM, EDIM, 0);
    gemm(yb, Wkt[l], nullptr, nullptr, kb, EDIM, EDIM, 0);
    gemm(yb, Wvt[l], nullptr, nullptr, vb, EDIM, EDIM, 0);
    // FAVOR+
    stab_init_kernel<<<1, 1, 0, stream>>>(stabp);
    stabmax_kernel<<<HN * ACH, 256, 0, stream>>>(kb, proj_l, stabp);
    ctx_kernel<<<HN * ACH, 256, 0, stream>>>(kb, vb, proj_l, stabp, pctx, pks);
    reduce_ctx_kernel<<<HN * MF * DHD / 256, 256, 0, stream>>>(pctx, ctxb);
    reduce_ksum_kernel<<<HN * MF / 256, 256, 0, stream>>>(pks, ksb);
    attn_out_kernel<<<HN * ACH, 256, 0, stream>>>(qb, proj_l, ctxb, ksb, yb);
    // h1 = h + a @ Wo + bo  -> qb
    gemm(yb, Wot[l], bo + l * EDIM, hb, qb, EDIM, EDIM, 0);
    // y2 = LN(h1) -> kb
    ln_bf16<<<NTOK / 4, 256, 0, stream>>>(qb, nullptr, lbg + l * EDIM, lbb + l * EDIM, kb);
    // h2 = h1 + gelu(y2@Wf1+bf1)@Wf2 + bf2 -> vb
    gemm(kb, Wf1t[l], bf1 + l * FDIM, nullptr, hid, EDIM, FDIM, 1);
    gemm(hid, Wf2t[l], bf2 + l * EDIM, qb, vb, FDIM, EDIM, 0);
    // attn_out = h2 @ Wpo + bpo -> yb ; h = LN(h + attn_out) -> hb
    gemm(vb, Wpot[l], bpo + l * EDIM, nullptr, yb, EDIM, EDIM, 0);
    ln_bf16<<<NTOK / 4, 256, 0, stream>>>(hb, yb, n1g + l * EDIM, n1b + l * EDIM, hb);
    // ffn = relu(h@Wn1+bn1)@Wn2+bn2 -> yb ; h = LN(h + ffn) -> hb
    gemm(hb, Wn1t[l], bn1 + l * FDIM, nullptr, hid, EDIM, FDIM, 2);
    gemm(hid, Wn2t[l], bn2 + l * EDIM, nullptr, yb, FDIM, EDIM, 0);
    ln_bf16<<<NTOK / 4, 256, 0, stream>>>(hb, yb, n2g + l * EDIM, n2b + l * EDIM, hb);
  }

  cls_kernel<<<NTOK / 4, 256, 0, stream>>>(hb, Wc, bc, (float*)d_out);
}

// Round 3
// 864.092 us; speedup vs baseline: 8.8888x; 3.8603x over previous
//
#include <hip/hip_runtime.h>
#include <math.h>

// ---------------- problem constants ----------------
#define NTOK  65536
#define EDIM  128
#define HN    4
#define DHD   32
#define MF    256
#define LLAYERS 2
#define INDIM 512
#define FDIM  512
#define CR    512            // ctx-pass rows per block
#define NCHK  (NTOK/CR)      // 128 chunks

#define DN    0.4204482076268573f     // 32^-0.25
#define DN2   0.17677669529663687f    // 32^-0.5
#define KEPS  1e-4f

typedef unsigned short u16;
typedef unsigned int   u32;
typedef __attribute__((ext_vector_type(8))) __bf16 bf16x8;
typedef __attribute__((ext_vector_type(4))) float  f32x4;

__device__ __forceinline__ u16 f2bf(float f){
  u32 u = __float_as_uint(f);
  u32 r = (u + 0x7fffu + ((u >> 16) & 1u)) >> 16;   // RNE
  return (u16)r;
}
__device__ __forceinline__ float bf2f(u16 h){ return __uint_as_float(((u32)h) << 16); }

__device__ __forceinline__ void gload_lds16(const void* g, void* l){
  __builtin_amdgcn_global_load_lds(
      (const __attribute__((address_space(1))) u32*)g,
      (__attribute__((address_space(3))) u32*)l, 16, 0, 0);
}

// ---- ordered-uint float max encoding (deterministic global atomic max) ----
__device__ __forceinline__ unsigned f2ord(float f){
  unsigned u = __float_as_uint(f);
  return (u & 0x80000000u) ? ~u : (u | 0x80000000u);
}
__device__ __forceinline__ float ord2f(unsigned e){
  unsigned u = (e & 0x80000000u) ? (e & 0x7fffffffu) : ~e;
  return __uint_as_float(u);
}

// ---------------- fp32 -> bf16 bulk convert (x) ----------------
__global__ __launch_bounds__(256) void cvt_bf16_4(const float4* __restrict__ src,
                                                  ushort4* __restrict__ dst){
  size_t i = (size_t)blockIdx.x * 256 + threadIdx.x;
  float4 f = src[i];
  ushort4 o;
  o.x = f2bf(f.x); o.y = f2bf(f.y); o.z = f2bf(f.z); o.w = f2bf(f.w);
  dst[i] = o;
}

// ---------------- weight transpose+convert: dst[j*K+k] = bf16(src[k*J+j]) ----------------
__global__ __launch_bounds__(256) void tpose_kernel(const float* __restrict__ src,
                                                    u16* __restrict__ dst, int K, int J){
  int idx = blockIdx.x * 256 + threadIdx.x;
  int j = idx / K, k = idx - j * K;
  dst[idx] = f2bf(src[(size_t)k * J + j]);
}

// ---------------- proj convert with dn fold: pjb[m][d] = bf16(proj[m][d]*DN) ----------------
__global__ __launch_bounds__(256) void pjcvt_kernel(const float* __restrict__ p,
                                                    u16* __restrict__ o){
  int i = blockIdx.x * 256 + threadIdx.x;
  o[i] = f2bf(p[i] * DN);
}

// ---------------- per-head V transpose: VT[h][d][n] = V[n][h*32+d] ----------------
__global__ __launch_bounds__(256) void vt_kernel(const u16* __restrict__ Vm,
                                                 u16* __restrict__ VT){
  __shared__ u16 t[32][72];
  const int tid = threadIdx.x;
  const int h = blockIdx.y; const int n0 = blockIdx.x * 64;
  { int row = tid >> 2, seg = tid & 3;
    uint4 v = *reinterpret_cast<const uint4*>(Vm + (size_t)(n0 + row) * EDIM + h * DHD + seg * 8);
    u32 wds[4] = {v.x, v.y, v.z, v.w};
#pragma unroll
    for (int i = 0; i < 4; ++i) {
      t[seg * 8 + 2 * i][row]     = (u16)(wds[i] & 0xffff);
      t[seg * 8 + 2 * i + 1][row] = (u16)(wds[i] >> 16);
    } }
  __syncthreads();
  { int d = tid >> 3, part = tid & 7;
    uint4 o;
    u32 w0 = (u32)t[d][part * 8 + 0] | ((u32)t[d][part * 8 + 1] << 16);
    u32 w1 = (u32)t[d][part * 8 + 2] | ((u32)t[d][part * 8 + 3] << 16);
    u32 w2 = (u32)t[d][part * 8 + 4] | ((u32)t[d][part * 8 + 5] << 16);
    u32 w3 = (u32)t[d][part * 8 + 6] | ((u32)t[d][part * 8 + 7] << 16);
    o.x = w0; o.y = w1; o.z = w2; o.w = w3;
    *reinterpret_cast<uint4*>(VT + (size_t)(h * DHD + d) * NTOK + n0 + part * 8) = o; }
}

// ---------------- per-row diag: Dg[h][n] = 0.5*dn^2*sum(x[n,h,:]^2) ----------------
__global__ __launch_bounds__(256) void diag_kernel(const u16* __restrict__ X,
                                                   float* __restrict__ Dg){
  const int tid = threadIdx.x;
  const int h = blockIdx.y; const int n0 = blockIdx.x * 64;
  int row = tid >> 2, seg = tid & 3;
  uint4 v = *reinterpret_cast<const uint4*>(X + (size_t)(n0 + row) * EDIM + h * DHD + seg * 8);
  u32 wds[4] = {v.x, v.y, v.z, v.w};
  float s = 0.f;
#pragma unroll
  for (int i = 0; i < 4; ++i) {
    float a = bf2f((u16)(wds[i] & 0xffff)), b = bf2f((u16)(wds[i] >> 16));
    s += a * a + b * b;
  }
  s += __shfl_xor(s, 1); s += __shfl_xor(s, 2);
  if (seg == 0) Dg[(size_t)h * NTOK + n0 + row] = 0.5f * DN2 * s;
}

// ---------------- bf16 MFMA GEMM (unchanged from R2) ----------------
__global__ __launch_bounds__(256) void gemm_bf16(
    const u16* __restrict__ A, const u16* __restrict__ Bt,
    const float* __restrict__ bias, const u16* __restrict__ res,
    u16* __restrict__ C, int K, int J, int op)
{
  __shared__ u16 Al[128 * 32];
  __shared__ u16 Bl[128 * 32];
  const int tid  = threadIdx.x;
  const int lane = tid & 63;
  const int w    = tid >> 6;
  const int wr   = w >> 1, wc = w & 1;
  const int n0   = blockIdx.x * 128;
  const int jb   = blockIdx.y * 128;

  f32x4 acc[4][4];
#pragma unroll
  for (int m = 0; m < 4; ++m)
#pragma unroll
    for (int n = 0; n < 4; ++n) acc[m][n] = (f32x4){0.f, 0.f, 0.f, 0.f};

  const int srow = lane >> 2;
  const int scol = (lane & 3) * 8;
  const u16* ga0 = A  + (size_t)(n0 + (w * 2 + 0) * 16 + srow) * K + scol;
  const u16* ga1 = A  + (size_t)(n0 + (w * 2 + 1) * 16 + srow) * K + scol;
  const u16* gb0 = Bt + (size_t)(jb + (w * 2 + 0) * 16 + srow) * K + scol;
  const u16* gb1 = Bt + (size_t)(jb + (w * 2 + 1) * 16 + srow) * K + scol;
  u16* la0 = &Al[(w * 2 + 0) * 512];
  u16* la1 = &Al[(w * 2 + 1) * 512];
  u16* lb0 = &Bl[(w * 2 + 0) * 512];
  u16* lb1 = &Bl[(w * 2 + 1) * 512];

  int aidx[4], bidx[4];
#pragma unroll
  for (int m = 0; m < 4; ++m) aidx[m] = (wr * 64 + m * 16 + (lane & 15)) * 32 + (lane >> 4) * 8;
#pragma unroll
  for (int n = 0; n < 4; ++n) bidx[n] = (wc * 64 + n * 16 + (lane & 15)) * 32 + (lane >> 4) * 8;

  for (int k0 = 0; k0 < K; k0 += 32) {
    __syncthreads();
    gload_lds16(ga0 + k0, la0);
    gload_lds16(ga1 + k0, la1);
    gload_lds16(gb0 + k0, lb0);
    gload_lds16(gb1 + k0, lb1);
    __syncthreads();
    bf16x8 af[4], bfg[4];
#pragma unroll
    for (int m = 0; m < 4; ++m) af[m]  = *reinterpret_cast<const bf16x8*>(&Al[aidx[m]]);
#pragma unroll
    for (int n = 0; n < 4; ++n) bfg[n] = *reinterpret_cast<const bf16x8*>(&Bl[bidx[n]]);
#pragma unroll
    for (int m = 0; m < 4; ++m)
#pragma unroll
      for (int n = 0; n < 4; ++n)
        acc[m][n] = __builtin_amdgcn_mfma_f32_16x16x32_bf16(af[m], bfg[n], acc[m][n], 0, 0, 0);
  }

  const int col0 = jb + wc * 64 + (lane & 15);
  const int row0 = n0 + wr * 64 + (lane >> 4) * 4;
  float bv[4];
#pragma unroll
  for (int n = 0; n < 4; ++n) bv[n] = bias ? bias[col0 + n * 16] : 0.f;
#pragma unroll
  for (int m = 0; m < 4; ++m) {
#pragma unroll
    for (int n = 0; n < 4; ++n) {
      const int gcol = col0 + n * 16;
#pragma unroll
      for (int j = 0; j < 4; ++j) {
        const int grow = row0 + m * 16 + j;
        float v = acc[m][n][j] + bv[n];
        if (op == 1)      v = 0.5f * v * (1.f + erff(v * 0.70710678118654752f));
        else if (op == 2) v = fmaxf(v, 0.f);
        if (res) v += bf2f(res[(size_t)grow * J + gcol]);
        C[(size_t)grow * J + gcol] = f2bf(v);
      }
    }
  }
}

// ---------------- LayerNorm (bf16 io) ----------------
__global__ __launch_bounds__(256) void ln_bf16(
    const u16* __restrict__ X, const u16* __restrict__ R,
    const float* __restrict__ g, const float* __restrict__ b,
    u16* __restrict__ O)
{
  const int lane = threadIdx.x & 63, wv = threadIdx.x >> 6;
  const int n = blockIdx.x * 4 + wv;
  const size_t ub = (size_t)n * 64 + lane;
  u32 u = ((const u32*)X)[ub];
  float e0 = bf2f((u16)(u & 0xffff)), e1 = bf2f((u16)(u >> 16));
  if (R) {
    u32 ru = ((const u32*)R)[ub];
    e0 += bf2f((u16)(ru & 0xffff)); e1 += bf2f((u16)(ru >> 16));
  }
  float s = e0 + e1;
#pragma unroll
  for (int o = 1; o < 64; o <<= 1) s += __shfl_xor(s, o);
  float mu = s * (1.f / 128.f);
  float d0 = e0 - mu, d1 = e1 - mu;
  float v = d0 * d0 + d1 * d1;
#pragma unroll
  for (int o = 1; o < 64; o <<= 1) v += __shfl_xor(v, o);
  float rs = rsqrtf(v * (1.f / 128.f) + 1e-5f);
  float o0 = d0 * rs * g[2 * lane]     + b[2 * lane];
  float o1 = d1 * rs * g[2 * lane + 1] + b[2 * lane + 1];
  ((u32*)O)[ub] = (u32)f2bf(o0) | ((u32)f2bf(o1) << 16);
}

// ---------------- stab: global max of dd_k via MFMA ----------------
__global__ void stab_init_kernel(unsigned* p){ *p = 0x007FFFFFu; /* f2ord(-inf) */ }

__global__ __launch_bounds__(256) void smax_kernel(
    const u16* __restrict__ Km, const u16* __restrict__ pjb,
    unsigned* __restrict__ stabp)
{
  __shared__ float wred[4];
  const int tid = threadIdx.x, lane = tid & 63, w = tid >> 6;
  const int h = blockIdx.y;
  const int n0 = blockIdx.x * 256 + w * 64;
  const int g = lane >> 4, c = lane & 15;
  bf16x8 af[4];
#pragma unroll
  for (int mf = 0; mf < 4; ++mf)
    af[mf] = *reinterpret_cast<const bf16x8*>(
        Km + (size_t)(n0 + mf * 16 + c) * EDIM + h * DHD + g * 8);
  float lm = -3.4e38f;
  const f32x4 z = (f32x4){0.f, 0.f, 0.f, 0.f};
#pragma unroll
  for (int jf = 0; jf < 16; ++jf) {
    bf16x8 bfg = *reinterpret_cast<const bf16x8*>(pjb + (jf * 16 + c) * DHD + g * 8);
#pragma unroll
    for (int mf = 0; mf < 4; ++mf) {
      f32x4 d = __builtin_amdgcn_mfma_f32_16x16x32_bf16(af[mf], bfg, z, 0, 0, 0);
      lm = fmaxf(lm, fmaxf(fmaxf(d[0], d[1]), fmaxf(d[2], d[3])));
    }
  }
#pragma unroll
  for (int o = 1; o < 64; o <<= 1) lm = fmaxf(lm, __shfl_xor(lm, o));
  if (lane == 0) wred[w] = lm;
  __syncthreads();
  if (tid == 0)
    atomicMax(stabp, f2ord(fmaxf(fmaxf(wred[0], wred[1]), fmaxf(wred[2], wred[3]))));
}

// ---------------- ctx pass: kf via MFMA dd, ctx += kf^T @ V via MFMA ----------------
// grid (NCHK, H), 256 thr. Wave w owns m-features 64w..64w+63; barrier-free.
__global__ __launch_bounds__(256) void ctxk_kernel(
    const u16* __restrict__ Km, const u16* __restrict__ VT,
    const u16* __restrict__ pjb, const float* __restrict__ kdiag,
    const unsigned* __restrict__ stabp,
    float* __restrict__ pctx, float* __restrict__ pks)
{
  __shared__ __align__(16) u16 kfT[256 * 40];   // [m][row0..31], stride 40
  const int tid = threadIdx.x, lane = tid & 63, w = tid >> 6;
  const int h = blockIdx.y, ch = blockIdx.x;
  const int n0 = ch * CR;
  const int g = lane >> 4, c = lane & 15;
  const float stab = ord2f(*stabp);
  const f32x4 z = (f32x4){0.f, 0.f, 0.f, 0.f};

  bf16x8 pf[4];
#pragma unroll
  for (int jf = 0; jf < 4; ++jf)
    pf[jf] = *reinterpret_cast<const bf16x8*>(pjb + ((w * 4 + jf) * 16 + c) * DHD + g * 8);

  f32x4 cacc[4][2];
#pragma unroll
  for (int mf = 0; mf < 4; ++mf)
#pragma unroll
    for (int df = 0; df < 2; ++df) cacc[mf][df] = z;
  float ksacc[4] = {0.f, 0.f, 0.f, 0.f};

  for (int s = 0; s < CR / 32; ++s) {
    const int rbase = n0 + s * 32;
    bf16x8 af[2];
#pragma unroll
    for (int rf = 0; rf < 2; ++rf)
      af[rf] = *reinterpret_cast<const bf16x8*>(
          Km + (size_t)(rbase + rf * 16 + c) * EDIM + h * DHD + g * 8);
#pragma unroll
    for (int rf = 0; rf < 2; ++rf) {
      float dg[4];
#pragma unroll
      for (int r = 0; r < 4; ++r)
        dg[r] = kdiag[(size_t)h * NTOK + rbase + rf * 16 + 4 * g + r] + stab;
#pragma unroll
      for (int jf = 0; jf < 4; ++jf) {
        f32x4 d = __builtin_amdgcn_mfma_f32_16x16x32_bf16(af[rf], pf[jf], z, 0, 0, 0);
        u16 b0 = f2bf(__expf(d[0] - dg[0]) + KEPS);
        u16 b1 = f2bf(__expf(d[1] - dg[1]) + KEPS);
        u16 b2 = f2bf(__expf(d[2] - dg[2]) + KEPS);
        u16 b3 = f2bf(__expf(d[3] - dg[3]) + KEPS);
        uint2 pk;
        pk.x = (u32)b0 | ((u32)b1 << 16);
        pk.y = (u32)b2 | ((u32)b3 << 16);
        *reinterpret_cast<uint2*>(&kfT[(size_t)(w * 64 + jf * 16 + c) * 40 + rf * 16 + 4 * g]) = pk;
        ksacc[jf] += bf2f(b0) + bf2f(b1) + bf2f(b2) + bf2f(b3);
      }
    }
    // wave-private strip: no barrier; compiler orders via lgkmcnt
#pragma unroll
    for (int mf = 0; mf < 4; ++mf) {
      bf16x8 a = *reinterpret_cast<const bf16x8*>(&kfT[(size_t)(w * 64 + mf * 16 + c) * 40 + g * 8]);
#pragma unroll
      for (int df = 0; df < 2; ++df) {
        bf16x8 b = *reinterpret_cast<const bf16x8*>(
            VT + (size_t)(h * DHD + df * 16 + c) * NTOK + rbase + g * 8);
        cacc[mf][df] = __builtin_amdgcn_mfma_f32_16x16x32_bf16(a, b, cacc[mf][df], 0, 0, 0);
      }
    }
  }
  // ksum partials: reduce over g lanes
#pragma unroll
  for (int jf = 0; jf < 4; ++jf) {
    float v = ksacc[jf];
    v += __shfl_xor(v, 16); v += __shfl_xor(v, 32);
    if (g == 0) pks[((size_t)h * NCHK + ch) * MF + w * 64 + jf * 16 + c] = v;
  }
  // ctx partials: C layout row=m-feat=(4g+r), col=d=c
#pragma unroll
  for (int mf = 0; mf < 4; ++mf)
#pragma unroll
    for (int df = 0; df < 2; ++df)
#pragma unroll
      for (int r = 0; r < 4; ++r) {
        int m = w * 64 + mf * 16 + 4 * g + r;
        int d = df * 16 + c;
        pctx[(((size_t)h * NCHK + ch) * MF + m) * DHD + d] = cacc[mf][df][r];
      }
}

// ---------------- reduce partials -> ctxT bf16 [H][32][256], ksum [H][256] ----------------
__global__ __launch_bounds__(256) void reduce_ctx_kernel(
    const float* __restrict__ p, u16* __restrict__ ctxT)
{
  int idx = blockIdx.x * 256 + threadIdx.x;     // h*8192 + m*32 + d
  int h = idx >> 13, md = idx & 8191;
  int m = md >> 5, d = md & 31;
  float s = 0.f;
  for (int c = 0; c < NCHK; ++c) s += p[((size_t)h * NCHK + c) * 8192 + md];
  ctxT[(size_t)h * 8192 + d * MF + m] = f2bf(s);
}

__global__ __launch_bounds__(256) void reduce_ks_kernel(
    const float* __restrict__ p, float* __restrict__ ks)
{
  int idx = blockIdx.x * 256 + threadIdx.x;     // h*256 + m
  int h = idx >> 8, m = idx & 255;
  float s = 0.f;
  for (int c = 0; c < NCHK; ++c) s += p[((size_t)h * NCHK + c) * MF + m];
  ks[idx] = s;
}

// ---------------- qf + out via MFMA ----------------
// grid (NTOK/128, H), 256 thr; wave w owns rows [bx*128+w*32, +32)
__global__ __launch_bounds__(256) void qout_kernel(
    const u16* __restrict__ Qm, const u16* __restrict__ pjb,
    const u16* __restrict__ ctxT, const float* __restrict__ ksg,
    const float* __restrict__ qdiag, u16* __restrict__ Am)
{
  __shared__ __align__(16) u16 qfs[4][32 * 40];  // per-wave strip [row][m_local], stride 40
  const int tid = threadIdx.x, lane = tid & 63, w = tid >> 6;
  const int h = blockIdx.y;
  const int n0 = blockIdx.x * 128 + w * 32;
  const int g = lane >> 4, c = lane & 15;
  const f32x4 z = (f32x4){0.f, 0.f, 0.f, 0.f};

  bf16x8 af[2];
#pragma unroll
  for (int rf = 0; rf < 2; ++rf)
    af[rf] = *reinterpret_cast<const bf16x8*>(
        Qm + (size_t)(n0 + rf * 16 + c) * EDIM + h * DHD + g * 8);

  // pass 1: per-row max of dd
  float rmax[2][4];
#pragma unroll
  for (int rf = 0; rf < 2; ++rf)
#pragma unroll
    for (int r = 0; r < 4; ++r) rmax[rf][r] = -3.4e38f;
#pragma unroll
  for (int jf = 0; jf < 16; ++jf) {
    bf16x8 b = *reinterpret_cast<const bf16x8*>(pjb + (jf * 16 + c) * DHD + g * 8);
#pragma unroll
    for (int rf = 0; rf < 2; ++rf) {
      f32x4 d = __builtin_amdgcn_mfma_f32_16x16x32_bf16(af[rf], b, z, 0, 0, 0);
#pragma unroll
      for (int r = 0; r < 4; ++r) rmax[rf][r] = fmaxf(rmax[rf][r], d[r]);
    }
  }
#pragma unroll
  for (int rf = 0; rf < 2; ++rf)
#pragma unroll
    for (int r = 0; r < 4; ++r) {
      float v = rmax[rf][r];
      v = fmaxf(v, __shfl_xor(v, 1)); v = fmaxf(v, __shfl_xor(v, 2));
      v = fmaxf(v, __shfl_xor(v, 4)); v = fmaxf(v, __shfl_xor(v, 8));
      rmax[rf][r] = v;
    }
  float crow[2][4];
#pragma unroll
  for (int rf = 0; rf < 2; ++rf)
#pragma unroll
    for (int r = 0; r < 4; ++r)
      crow[rf][r] = qdiag[(size_t)h * NTOK + n0 + rf * 16 + 4 * g + r] + rmax[rf][r];

  // pass 2: qf -> strip -> out MFMA; D via dot
  f32x4 oacc[2][2];
#pragma unroll
  for (int rf = 0; rf < 2; ++rf)
#pragma unroll
    for (int df = 0; df < 2; ++df) oacc[rf][df] = z;
  float Dacc[2][4];
#pragma unroll
  for (int rf = 0; rf < 2; ++rf)
#pragma unroll
    for (int r = 0; r < 4; ++r) Dacc[rf][r] = 0.f;

  for (int ks = 0; ks < 8; ++ks) {
#pragma unroll
    for (int jj = 0; jj < 2; ++jj) {
      const int jf = ks * 2 + jj;
      bf16x8 b = *reinterpret_cast<const bf16x8*>(pjb + (jf * 16 + c) * DHD + g * 8);
      const float ksv = ksg[h * MF + jf * 16 + c];
#pragma unroll
      for (int rf = 0; rf < 2; ++rf) {
        f32x4 d = __builtin_amdgcn_mfma_f32_16x16x32_bf16(af[rf], b, z, 0, 0, 0);
#pragma unroll
        for (int r = 0; r < 4; ++r) {
          float q = __expf(d[r] - crow[rf][r]) + KEPS;
          u16 qb_ = f2bf(q);
          qfs[w][(rf * 16 + 4 * g + r) * 40 + jj * 16 + c] = qb_;
          Dacc[rf][r] += bf2f(qb_) * ksv;
        }
      }
    }
    // wave-private strip: no barrier needed
#pragma unroll
    for (int rf = 0; rf < 2; ++rf) {
      bf16x8 a = *reinterpret_cast<const bf16x8*>(&qfs[w][(rf * 16 + c) * 40 + g * 8]);
#pragma unroll
      for (int df = 0; df < 2; ++df) {
        bf16x8 bc = *reinterpret_cast<const bf16x8*>(
            ctxT + (size_t)(h * DHD + df * 16 + c) * MF + ks * 32 + g * 8);
        oacc[rf][df] = __builtin_amdgcn_mfma_f32_16x16x32_bf16(a, bc, oacc[rf][df], 0, 0, 0);
      }
    }
  }
#pragma unroll
  for (int rf = 0; rf < 2; ++rf)
#pragma unroll
    for (int r = 0; r < 4; ++r) {
      float v = Dacc[rf][r];
      v += __shfl_xor(v, 1); v += __shfl_xor(v, 2);
      v += __shfl_xor(v, 4); v += __shfl_xor(v, 8);
      Dacc[rf][r] = v;
    }
#pragma unroll
  for (int rf = 0; rf < 2; ++rf)
#pragma unroll
    for (int df = 0; df < 2; ++df)
#pragma unroll
      for (int r = 0; r < 4; ++r)
        Am[(size_t)(n0 + rf * 16 + 4 * g + r) * EDIM + h * DHD + df * 16 + c] =
            f2bf(oacc[rf][df][r] / Dacc[rf][r]);
}

// ---------------- classifier ----------------
__global__ __launch_bounds__(256) void cls_kernel(
    const u16* __restrict__ Hm, const float* __restrict__ Wc,
    const float* __restrict__ bc, float* __restrict__ out)
{
  const int lane = threadIdx.x & 63, wv = threadIdx.x >> 6;
  const int n = blockIdx.x * 4 + wv;
  u32 u = ((const u32*)Hm)[(size_t)n * 64 + lane];
  float e0 = bf2f((u16)(u & 0xffff)), e1 = bf2f((u16)(u >> 16));
  float s = e0 * Wc[2 * lane] + e1 * Wc[2 * lane + 1];
#pragma unroll
  for (int o = 1; o < 64; o <<= 1) s += __shfl_xor(s, o);
  if (lane == 0) out[n] = 1.f / (1.f + expf(-(s + bc[0])));
}

// ---------------- host ----------------
extern "C" void kernel_launch(void* const* d_in, const int* in_sizes, int n_in,
                              void* d_out, int out_size, void* d_ws, size_t ws_size,
                              hipStream_t stream)
{
  const float* x    = (const float*)d_in[0];
  const float* Wpin = (const float*)d_in[1];
  const float* bpin = (const float*)d_in[2];
  const float* lag  = (const float*)d_in[3];
  const float* lab  = (const float*)d_in[4];
  const float* Wq   = (const float*)d_in[5];
  const float* Wk   = (const float*)d_in[6];
  const float* Wv   = (const float*)d_in[7];
  const float* Wo   = (const float*)d_in[8];
  const float* bo   = (const float*)d_in[9];
  const float* lbg  = (const float*)d_in[10];
  const float* lbb  = (const float*)d_in[11];
  const float* Wf1  = (const float*)d_in[12];
  const float* bf1  = (const float*)d_in[13];
  const float* Wf2  = (const float*)d_in[14];
  const float* bf2  = (const float*)d_in[15];
  const float* Wpo  = (const float*)d_in[16];
  const float* bpo  = (const float*)d_in[17];
  const float* n1g  = (const float*)d_in[18];
  const float* n1b  = (const float*)d_in[19];
  const float* Wn1  = (const float*)d_in[20];
  const float* bn1  = (const float*)d_in[21];
  const float* Wn2  = (const float*)d_in[22];
  const float* bn2  = (const float*)d_in[23];
  const float* n2g  = (const float*)d_in[24];
  const float* n2b  = (const float*)d_in[25];
  const float* Wc   = (const float*)d_in[26];
  const float* bc   = (const float*)d_in[27];
  const float* proj = (const float*)d_in[28];

  size_t off = 0;
  char* base = (char*)d_ws;
  auto alloc = [&](size_t bytes) -> void* {
    void* p = base + off;
    off += (bytes + 255) & ~(size_t)255;
    return p;
  };
  u16* xbf = (u16*)alloc((size_t)NTOK * INDIM * 2);
  u16* hb  = (u16*)alloc((size_t)NTOK * EDIM * 2);
  u16* yb  = (u16*)alloc((size_t)NTOK * EDIM * 2);
  u16* qb  = (u16*)alloc((size_t)NTOK * EDIM * 2);
  u16* kb  = (u16*)alloc((size_t)NTOK * EDIM * 2);
  u16* vb  = (u16*)alloc((size_t)NTOK * EDIM * 2);
  u16* hid = (u16*)alloc((size_t)NTOK * FDIM * 2);
  u16* VT  = (u16*)alloc((size_t)HN * DHD * NTOK * 2);
  u16* pjb = (u16*)alloc((size_t)MF * DHD * 2);
  u16* ctxT = (u16*)alloc((size_t)HN * DHD * MF * 2);
  float* kdiag = (float*)alloc((size_t)HN * NTOK * 4);
  float* qdiag = (float*)alloc((size_t)HN * NTOK * 4);
  float* ksg  = (float*)alloc((size_t)HN * MF * 4);
  float* pctx = (float*)alloc((size_t)HN * NCHK * MF * DHD * 4);
  float* pks  = (float*)alloc((size_t)HN * NCHK * MF * 4);
  unsigned* stabp = (unsigned*)alloc(256);
  u16* wts = (u16*)alloc((size_t)753664 * 2);

  size_t wo = 0;
  u16* Wpint = wts + wo; wo += 512 * 128;
  u16 *Wqt[LLAYERS], *Wkt[LLAYERS], *Wvt[LLAYERS], *Wot[LLAYERS], *Wpot[LLAYERS];
  u16 *Wf1t[LLAYERS], *Wf2t[LLAYERS], *Wn1t[LLAYERS], *Wn2t[LLAYERS];
  for (int l = 0; l < LLAYERS; ++l) {
    Wqt[l]  = wts + wo; wo += 128 * 128;
    Wkt[l]  = wts + wo; wo += 128 * 128;
    Wvt[l]  = wts + wo; wo += 128 * 128;
    Wot[l]  = wts + wo; wo += 128 * 128;
    Wpot[l] = wts + wo; wo += 128 * 128;
    Wf1t[l] = wts + wo; wo += 128 * 512;
    Wf2t[l] = wts + wo; wo += 512 * 128;
    Wn1t[l] = wts + wo; wo += 128 * 512;
    Wn2t[l] = wts + wo; wo += 512 * 128;
  }

  cvt_bf16_4<<<(NTOK * INDIM / 4) / 256, 256, 0, stream>>>(
      (const float4*)x, (ushort4*)xbf);

  auto tp = [&](const float* s, u16* d, int K, int J) {
    tpose_kernel<<<(K * J) / 256, 256, 0, stream>>>(s, d, K, J);
  };
  tp(Wpin, Wpint, INDIM, EDIM);
  for (int l = 0; l < LLAYERS; ++l) {
    tp(Wq  + (size_t)l * 16384, Wqt[l],  128, 128);
    tp(Wk  + (size_t)l * 16384, Wkt[l],  128, 128);
    tp(Wv  + (size_t)l * 16384, Wvt[l],  128, 128);
    tp(Wo  + (size_t)l * 16384, Wot[l],  128, 128);
    tp(Wpo + (size_t)l * 16384, Wpot[l], 128, 128);
    tp(Wf1 + (size_t)l * 65536, Wf1t[l], 128, 512);
    tp(Wf2 + (size_t)l * 65536, Wf2t[l], 512, 128);
    tp(Wn1 + (size_t)l * 65536, Wn1t[l], 128, 512);
    tp(Wn2 + (size_t)l * 65536, Wn2t[l], 512, 128);
  }

  auto gemm = [&](const u16* A, const u16* Bt, const float* bias,
                  const u16* res, u16* C, int K, int J, int op) {
    dim3 grid(NTOK / 128, J / 128);
    gemm_bf16<<<grid, 256, 0, stream>>>(A, Bt, bias, res, C, K, J, op);
  };

  gemm(xbf, Wpint, bpin, nullptr, hb, INDIM, EDIM, 0);

  for (int l = 0; l < LLAYERS; ++l) {
    const float* proj_l = proj + (size_t)l * MF * DHD;

    ln_bf16<<<NTOK / 4, 256, 0, stream>>>(hb, nullptr, lag + l * EDIM, lab + l * EDIM, yb);
    gemm(yb, Wqt[l], nullptr, nullptr, qb, EDIM, EDIM, 0);
    gemm(yb, Wkt[l], nullptr, nullptr, kb, EDIM, EDIM, 0);
    gemm(yb, Wvt[l], nullptr, nullptr, vb, EDIM, EDIM, 0);

    // FAVOR+ (MFMA path)
    pjcvt_kernel<<<MF * DHD / 256, 256, 0, stream>>>(proj_l, pjb);
    vt_kernel<<<dim3(NTOK / 64, HN), 256, 0, stream>>>(vb, VT);
    diag_kernel<<<dim3(NTOK / 64, HN), 256, 0, stream>>>(kb, kdiag);
    diag_kernel<<<dim3(NTOK / 64, HN), 256, 0, stream>>>(qb, qdiag);
    stab_init_kernel<<<1, 1, 0, stream>>>(stabp);
    smax_kernel<<<dim3(NTOK / 256, HN), 256, 0, stream>>>(kb, pjb, stabp);
    ctxk_kernel<<<dim3(NCHK, HN), 256, 0, stream>>>(kb, VT, pjb, kdiag, stabp, pctx, pks);
    reduce_ctx_kernel<<<HN * MF * DHD / 256, 256, 0, stream>>>(pctx, ctxT);
    reduce_ks_kernel<<<HN * MF / 256, 256, 0, stream>>>(pks, ksg);
    qout_kernel<<<dim3(NTOK / 128, HN), 256, 0, stream>>>(qb, pjb, ctxT, ksg, qdiag, yb);

    gemm(yb, Wot[l], bo + l * EDIM, hb, qb, EDIM, EDIM, 0);
    ln_bf16<<<NTOK / 4, 256, 0, stream>>>(qb, nullptr, lbg + l * EDIM, lbb + l * EDIM, kb);
    gemm(kb, Wf1t[l], bf1 + l * FDIM, nullptr, hid, EDIM, FDIM, 1);
    gemm(hid, Wf2t[l], bf2 + l * EDIM, qb, vb, FDIM, EDIM, 0);
    gemm(vb, Wpot[l], bpo + l * EDIM, nullptr, yb, EDIM, EDIM, 0);
    ln_bf16<<<NTOK / 4, 256, 0, stream>>>(hb, yb, n1g + l * EDIM, n1b + l * EDIM, hb);
    gemm(hb, Wn1t[l], bn1 + l * FDIM, nullptr, hid, EDIM, FDIM, 2);
    gemm(hid, Wn2t[l], bn2 + l * EDIM, nullptr, yb, FDIM, EDIM, 0);
    ln_bf16<<<NTOK / 4, 256, 0, stream>>>(hb, yb, n2g + l * EDIM, n2b + l * EDIM, hb);
  }

  cls_kernel<<<NTOK / 4, 256, 0, stream>>>(hb, Wc, bc, (float*)d_out);
}

// Round 4
// 824.369 us; speedup vs baseline: 9.3172x; 1.0482x over previous
//
#include <hip/hip_runtime.h>
#include <math.h>

// ---------------- problem constants ----------------
#define NTOK  65536
#define EDIM  128
#define HN    4
#define DHD   32
#define MF    256
#define LLAYERS 2
#define INDIM 512
#define FDIM  512
#define CR    512            // ctx-pass rows per block
#define NCHK  (NTOK/CR)      // 128 chunks

#define DN    0.4204482076268573f     // 32^-0.25
#define DN2   0.17677669529663687f    // 32^-0.5
#define KEPS  1e-4f

typedef unsigned short u16;
typedef unsigned int   u32;
typedef __attribute__((ext_vector_type(8))) __bf16 bf16x8;
typedef __attribute__((ext_vector_type(4))) float  f32x4;

__device__ __forceinline__ u16 f2bf(float f){
  u32 u = __float_as_uint(f);
  u32 r = (u + 0x7fffu + ((u >> 16) & 1u)) >> 16;   // RNE
  return (u16)r;
}
__device__ __forceinline__ float bf2f(u16 h){ return __uint_as_float(((u32)h) << 16); }

__device__ __forceinline__ void gload_lds16(const void* g, void* l){
  __builtin_amdgcn_global_load_lds(
      (const __attribute__((address_space(1))) u32*)g,
      (__attribute__((address_space(3))) u32*)l, 16, 0, 0);
}

__device__ __forceinline__ unsigned f2ord(float f){
  unsigned u = __float_as_uint(f);
  return (u & 0x80000000u) ? ~u : (u | 0x80000000u);
}
__device__ __forceinline__ float ord2f(unsigned e){
  unsigned u = (e & 0x80000000u) ? (e & 0x7fffffffu) : ~e;
  return __uint_as_float(u);
}

// ---------------- prep: all weight transposes + proj scale + stab init ----------------
struct PrepArgs {
  const float* Wpin; const float* Wq; const float* Wk; const float* Wv;
  const float* Wo;   const float* Wpo; const float* Wf1; const float* Wf2;
  const float* Wn1;  const float* Wn2; const float* proj;
};

__global__ __launch_bounds__(256) void prep_kernel(PrepArgs a, u16* __restrict__ wts,
                                                   u16* __restrict__ pjb,
                                                   unsigned* __restrict__ stabp)
{
  int idx = blockIdx.x * 256 + threadIdx.x;
  if (idx == 0) { stabp[0] = 0x007FFFFFu; stabp[1] = 0x007FFFFFu; }
  const float* sp; u16* dp; int r, K, J;
  if      (idx <  65536) { sp = a.Wpin; dp = wts;          r = idx;          K = 512; J = 128; }
  else if (idx <  98304) { sp = a.Wq;   dp = wts +  65536; r = idx -  65536; K = 128; J = 128; }
  else if (idx < 131072) { sp = a.Wk;   dp = wts +  98304; r = idx -  98304; K = 128; J = 128; }
  else if (idx < 163840) { sp = a.Wv;   dp = wts + 131072; r = idx - 131072; K = 128; J = 128; }
  else if (idx < 196608) { sp = a.Wo;   dp = wts + 163840; r = idx - 163840; K = 128; J = 128; }
  else if (idx < 229376) { sp = a.Wpo;  dp = wts + 196608; r = idx - 196608; K = 128; J = 128; }
  else if (idx < 360448) { sp = a.Wf1;  dp = wts + 229376; r = idx - 229376; K = 128; J = 512; }
  else if (idx < 491520) { sp = a.Wf2;  dp = wts + 360448; r = idx - 360448; K = 512; J = 128; }
  else if (idx < 622592) { sp = a.Wn1;  dp = wts + 491520; r = idx - 491520; K = 128; J = 512; }
  else if (idx < 753664) { sp = a.Wn2;  dp = wts + 622592; r = idx - 622592; K = 512; J = 128; }
  else { int p = idx - 753664; pjb[p] = f2bf(a.proj[p] * DN); return; }
  int kj = K * J;
  int l = r / kj, rr = r - l * kj;
  int j = rr / K, k = rr - j * K;
  dp[r] = f2bf(sp[(size_t)l * kj + (size_t)k * J + j]);
}

// ---------------- fused bf16 MFMA GEMM ----------------
// LNM: 0 plain, 1 LN1(opt raw), 2 LN1+LN2, 3 LN1+classifier. A32: stage A from fp32.
// Tile 128x128, BK=32, 4 waves (2x2 of 64x64). LN modes require J==128.
template<int LNM, bool A32>
__global__ __launch_bounds__(256) void gemm_f(
    const u16* __restrict__ A, const float* __restrict__ Af,
    const u16* __restrict__ Bt,
    const float* __restrict__ bias, const u16* __restrict__ res,
    u16* __restrict__ outRaw, int K, int J, int op,
    const float* __restrict__ g1, const float* __restrict__ b1, u16* __restrict__ outL1,
    const float* __restrict__ g2, const float* __restrict__ b2, u16* __restrict__ outL2,
    const float* __restrict__ Wcp, const float* __restrict__ bcp, float* __restrict__ outCls)
{
  __shared__ u16 Al[128 * 32];
  __shared__ u16 Bl[128 * 32];
  __shared__ float lnred[2][2][64][2];
  const int tid  = threadIdx.x;
  const int lane = tid & 63;
  const int w    = tid >> 6;
  const int wr   = w >> 1, wc = w & 1;
  const int n0   = blockIdx.x * 128;
  const int jb   = blockIdx.y * 128;

  f32x4 acc[4][4];
#pragma unroll
  for (int m = 0; m < 4; ++m)
#pragma unroll
    for (int n = 0; n < 4; ++n) acc[m][n] = (f32x4){0.f, 0.f, 0.f, 0.f};

  const int srow = lane >> 2;
  const int scol = (lane & 3) * 8;
  const u16* ga0 = A  + (size_t)(n0 + (w * 2 + 0) * 16 + srow) * K + scol;
  const u16* ga1 = A  + (size_t)(n0 + (w * 2 + 1) * 16 + srow) * K + scol;
  const u16* gb0 = Bt + (size_t)(jb + (w * 2 + 0) * 16 + srow) * K + scol;
  const u16* gb1 = Bt + (size_t)(jb + (w * 2 + 1) * 16 + srow) * K + scol;
  u16* la0 = &Al[(w * 2 + 0) * 512];
  u16* la1 = &Al[(w * 2 + 1) * 512];
  u16* lb0 = &Bl[(w * 2 + 0) * 512];
  u16* lb1 = &Bl[(w * 2 + 1) * 512];

  int aidx[4], bidx[4];
#pragma unroll
  for (int m = 0; m < 4; ++m) aidx[m] = (wr * 64 + m * 16 + (lane & 15)) * 32 + (lane >> 4) * 8;
#pragma unroll
  for (int n = 0; n < 4; ++n) bidx[n] = (wc * 64 + n * 16 + (lane & 15)) * 32 + (lane >> 4) * 8;

  for (int k0 = 0; k0 < K; k0 += 32) {
    __syncthreads();
    if constexpr (A32) {
      const int r = tid >> 1, hf = tid & 1;
      const float* gp = Af + (size_t)(n0 + r) * K + k0 + hf * 16;
      float4 f0 = ((const float4*)gp)[0];
      float4 f1 = ((const float4*)gp)[1];
      float4 f2 = ((const float4*)gp)[2];
      float4 f3 = ((const float4*)gp)[3];
      uint4 w0, w1;
      w0.x = (u32)f2bf(f0.x) | ((u32)f2bf(f0.y) << 16);
      w0.y = (u32)f2bf(f0.z) | ((u32)f2bf(f0.w) << 16);
      w0.z = (u32)f2bf(f1.x) | ((u32)f2bf(f1.y) << 16);
      w0.w = (u32)f2bf(f1.z) | ((u32)f2bf(f1.w) << 16);
      w1.x = (u32)f2bf(f2.x) | ((u32)f2bf(f2.y) << 16);
      w1.y = (u32)f2bf(f2.z) | ((u32)f2bf(f2.w) << 16);
      w1.z = (u32)f2bf(f3.x) | ((u32)f2bf(f3.y) << 16);
      w1.w = (u32)f2bf(f3.z) | ((u32)f2bf(f3.w) << 16);
      *reinterpret_cast<uint4*>(&Al[r * 32 + hf * 16])     = w0;
      *reinterpret_cast<uint4*>(&Al[r * 32 + hf * 16 + 8]) = w1;
      gload_lds16(gb0 + k0, lb0);
      gload_lds16(gb1 + k0, lb1);
    } else {
      gload_lds16(ga0 + k0, la0);
      gload_lds16(ga1 + k0, la1);
      gload_lds16(gb0 + k0, lb0);
      gload_lds16(gb1 + k0, lb1);
    }
    __syncthreads();
    bf16x8 af[4], bfg[4];
#pragma unroll
    for (int m = 0; m < 4; ++m) af[m]  = *reinterpret_cast<const bf16x8*>(&Al[aidx[m]]);
#pragma unroll
    for (int n = 0; n < 4; ++n) bfg[n] = *reinterpret_cast<const bf16x8*>(&Bl[bidx[n]]);
#pragma unroll
    for (int m = 0; m < 4; ++m)
#pragma unroll
      for (int n = 0; n < 4; ++n)
        acc[m][n] = __builtin_amdgcn_mfma_f32_16x16x32_bf16(af[m], bfg[n], acc[m][n], 0, 0, 0);
  }

  // ---------- epilogue ----------
  const int colb = jb + wc * 64 + (lane & 15);       // + n*16
  const int rowb = n0 + wr * 64 + (lane >> 4) * 4;   // + m*16 + j
  float bv[4];
#pragma unroll
  for (int n = 0; n < 4; ++n) bv[n] = bias ? bias[colb + n * 16] : 0.f;

  float v[4][4][4];
#pragma unroll
  for (int m = 0; m < 4; ++m)
#pragma unroll
    for (int n = 0; n < 4; ++n)
#pragma unroll
      for (int j = 0; j < 4; ++j) {
        float t = acc[m][n][j] + bv[n];
        if (op == 1)      t = 0.5f * t * (1.f + erff(t * 0.70710678118654752f));
        else if (op == 2) t = fmaxf(t, 0.f);
        if (res) t += bf2f(res[(size_t)(rowb + m * 16 + j) * J + colb + n * 16]);
        v[m][n][j] = t;
      }

  if (outRaw) {
#pragma unroll
    for (int m = 0; m < 4; ++m)
#pragma unroll
      for (int n = 0; n < 4; ++n)
#pragma unroll
        for (int j = 0; j < 4; ++j)
          outRaw[(size_t)(rowb + m * 16 + j) * J + colb + n * 16] = f2bf(v[m][n][j]);
  }

  if constexpr (LNM > 0) {
    auto ln_apply = [&](const float* gp, const float* bp) {
      float rs[4][4], rq[4][4];
#pragma unroll
      for (int m = 0; m < 4; ++m)
#pragma unroll
        for (int j = 0; j < 4; ++j) {
          float s = 0.f, q = 0.f;
#pragma unroll
          for (int n = 0; n < 4; ++n) { float t = v[m][n][j]; s += t; q += t * t; }
          rs[m][j] = s; rq[m][j] = q;
        }
#pragma unroll
      for (int o = 1; o < 16; o <<= 1)
#pragma unroll
        for (int m = 0; m < 4; ++m)
#pragma unroll
          for (int j = 0; j < 4; ++j) {
            rs[m][j] += __shfl_xor(rs[m][j], o);
            rq[m][j] += __shfl_xor(rq[m][j], o);
          }
      __syncthreads();
      if ((lane & 15) == 0) {
#pragma unroll
        for (int m = 0; m < 4; ++m)
#pragma unroll
          for (int j = 0; j < 4; ++j) {
            int rloc = m * 16 + (lane >> 4) * 4 + j;
            lnred[wr][wc][rloc][0] = rs[m][j];
            lnred[wr][wc][rloc][1] = rq[m][j];
          }
      }
      __syncthreads();
      float gg[4], bb[4];
#pragma unroll
      for (int n = 0; n < 4; ++n) { gg[n] = gp[colb + n * 16]; bb[n] = bp[colb + n * 16]; }
#pragma unroll
      for (int m = 0; m < 4; ++m)
#pragma unroll
        for (int j = 0; j < 4; ++j) {
          int rloc = m * 16 + (lane >> 4) * 4 + j;
          float ts = rs[m][j] + lnred[wr][wc ^ 1][rloc][0];
          float tq = rq[m][j] + lnred[wr][wc ^ 1][rloc][1];
          float mu = ts * (1.f / 128.f);
          float rsig = rsqrtf(tq * (1.f / 128.f) - mu * mu + 1e-5f);
#pragma unroll
          for (int n = 0; n < 4; ++n)
            v[m][n][j] = (v[m][n][j] - mu) * rsig * gg[n] + bb[n];
        }
    };

    ln_apply(g1, b1);
    if (outL1) {
#pragma unroll
      for (int m = 0; m < 4; ++m)
#pragma unroll
        for (int n = 0; n < 4; ++n)
#pragma unroll
          for (int j = 0; j < 4; ++j)
            outL1[(size_t)(rowb + m * 16 + j) * J + colb + n * 16] = f2bf(v[m][n][j]);
    }
    if constexpr (LNM == 2) {
      ln_apply(g2, b2);
#pragma unroll
      for (int m = 0; m < 4; ++m)
#pragma unroll
        for (int n = 0; n < 4; ++n)
#pragma unroll
          for (int j = 0; j < 4; ++j)
            outL2[(size_t)(rowb + m * 16 + j) * J + colb + n * 16] = f2bf(v[m][n][j]);
    }
    if constexpr (LNM == 3) {
      const float bc0 = bcp[0];
      float wv[4];
#pragma unroll
      for (int n = 0; n < 4; ++n) wv[n] = Wcp[colb + n * 16];
      float dp[4][4];
#pragma unroll
      for (int m = 0; m < 4; ++m)
#pragma unroll
        for (int j = 0; j < 4; ++j) {
          float s = 0.f;
#pragma unroll
          for (int n = 0; n < 4; ++n) s += v[m][n][j] * wv[n];
          dp[m][j] = s;
        }
#pragma unroll
      for (int o = 1; o < 16; o <<= 1)
#pragma unroll
        for (int m = 0; m < 4; ++m)
#pragma unroll
          for (int j = 0; j < 4; ++j) dp[m][j] += __shfl_xor(dp[m][j], o);
      __syncthreads();
      if ((lane & 15) == 0) {
#pragma unroll
        for (int m = 0; m < 4; ++m)
#pragma unroll
          for (int j = 0; j < 4; ++j)
            lnred[wr][wc][m * 16 + (lane >> 4) * 4 + j][0] = dp[m][j];
      }
      __syncthreads();
      if (wc == 0 && (lane & 15) == 0) {
#pragma unroll
        for (int m = 0; m < 4; ++m)
#pragma unroll
          for (int j = 0; j < 4; ++j) {
            int rloc = m * 16 + (lane >> 4) * 4 + j;
            float t = dp[m][j] + lnred[wr][1][rloc][0] + bc0;
            outCls[n0 + wr * 64 + rloc] = 1.f / (1.f + expf(-t));
          }
      }
    }
  }
}

// ---------------- per-head V transpose: VT[h][d][n] = V[n][h*32+d] ----------------
__global__ __launch_bounds__(256) void vt_kernel(const u16* __restrict__ Vm,
                                                 u16* __restrict__ VT){
  __shared__ u16 t[32][72];
  const int tid = threadIdx.x;
  const int h = blockIdx.y; const int n0 = blockIdx.x * 64;
  { int row = tid >> 2, seg = tid & 3;
    uint4 v = *reinterpret_cast<const uint4*>(Vm + (size_t)(n0 + row) * EDIM + h * DHD + seg * 8);
    u32 wds[4] = {v.x, v.y, v.z, v.w};
#pragma unroll
    for (int i = 0; i < 4; ++i) {
      t[seg * 8 + 2 * i][row]     = (u16)(wds[i] & 0xffff);
      t[seg * 8 + 2 * i + 1][row] = (u16)(wds[i] >> 16);
    } }
  __syncthreads();
  { int d = tid >> 3, part = tid & 7;
    uint4 o;
    o.x = (u32)t[d][part * 8 + 0] | ((u32)t[d][part * 8 + 1] << 16);
    o.y = (u32)t[d][part * 8 + 2] | ((u32)t[d][part * 8 + 3] << 16);
    o.z = (u32)t[d][part * 8 + 4] | ((u32)t[d][part * 8 + 5] << 16);
    o.w = (u32)t[d][part * 8 + 6] | ((u32)t[d][part * 8 + 7] << 16);
    *reinterpret_cast<uint4*>(VT + (size_t)(h * DHD + d) * NTOK + n0 + part * 8) = o; }
}

// ---------------- stab: global max of dd_k via MFMA ----------------
__global__ __launch_bounds__(256) void smax_kernel(
    const u16* __restrict__ Km, const u16* __restrict__ pjb,
    unsigned* __restrict__ stabp)
{
  __shared__ float wred[4];
  const int tid = threadIdx.x, lane = tid & 63, w = tid >> 6;
  const int h = blockIdx.y;
  const int n0 = blockIdx.x * 256 + w * 64;
  const int g = lane >> 4, c = lane & 15;
  bf16x8 af[4];
#pragma unroll
  for (int mf = 0; mf < 4; ++mf)
    af[mf] = *reinterpret_cast<const bf16x8*>(
        Km + (size_t)(n0 + mf * 16 + c) * EDIM + h * DHD + g * 8);
  float lm = -3.4e38f;
  const f32x4 z = (f32x4){0.f, 0.f, 0.f, 0.f};
#pragma unroll
  for (int jf = 0; jf < 16; ++jf) {
    bf16x8 bfg = *reinterpret_cast<const bf16x8*>(pjb + (jf * 16 + c) * DHD + g * 8);
#pragma unroll
    for (int mf = 0; mf < 4; ++mf) {
      f32x4 d = __builtin_amdgcn_mfma_f32_16x16x32_bf16(af[mf], bfg, z, 0, 0, 0);
      lm = fmaxf(lm, fmaxf(fmaxf(d[0], d[1]), fmaxf(d[2], d[3])));
    }
  }
#pragma unroll
  for (int o = 1; o < 64; o <<= 1) lm = fmaxf(lm, __shfl_xor(lm, o));
  if (lane == 0) wred[w] = lm;
  __syncthreads();
  if (tid == 0)
    atomicMax(stabp, f2ord(fmaxf(fmaxf(wred[0], wred[1]), fmaxf(wred[2], wred[3]))));
}

// ---------------- ctx pass: kf via MFMA dd (diag in-kernel), ctx += kf^T @ V ----------------
__global__ __launch_bounds__(256) void ctxk_kernel(
    const u16* __restrict__ Km, const u16* __restrict__ VT,
    const u16* __restrict__ pjb, const unsigned* __restrict__ stabp,
    float* __restrict__ pctx, float* __restrict__ pks)
{
  __shared__ __align__(16) u16 kfT[256 * 40];
  const int tid = threadIdx.x, lane = tid & 63, w = tid >> 6;
  const int h = blockIdx.y, ch = blockIdx.x;
  const int n0 = ch * CR;
  const int g = lane >> 4, c = lane & 15;
  const float stab = ord2f(*stabp);
  const f32x4 z = (f32x4){0.f, 0.f, 0.f, 0.f};

  bf16x8 pf[4];
#pragma unroll
  for (int jf = 0; jf < 4; ++jf)
    pf[jf] = *reinterpret_cast<const bf16x8*>(pjb + ((w * 4 + jf) * 16 + c) * DHD + g * 8);

  f32x4 cacc[4][2];
#pragma unroll
  for (int mf = 0; mf < 4; ++mf)
#pragma unroll
    for (int df = 0; df < 2; ++df) cacc[mf][df] = z;
  float ksacc[4] = {0.f, 0.f, 0.f, 0.f};

  for (int s = 0; s < CR / 32; ++s) {
    const int rbase = n0 + s * 32;
    bf16x8 af[2];
    float s2[2];
#pragma unroll
    for (int rf = 0; rf < 2; ++rf) {
      af[rf] = *reinterpret_cast<const bf16x8*>(
          Km + (size_t)(rbase + rf * 16 + c) * EDIM + h * DHD + g * 8);
      uint4 ui = *reinterpret_cast<const uint4*>(&af[rf]);
      u32 wd[4] = {ui.x, ui.y, ui.z, ui.w};
      float ss = 0.f;
#pragma unroll
      for (int i = 0; i < 4; ++i) {
        float a = bf2f((u16)(wd[i] & 0xffff)), b = bf2f((u16)(wd[i] >> 16));
        ss += a * a + b * b;
      }
      ss += __shfl_xor(ss, 16); ss += __shfl_xor(ss, 32);
      s2[rf] = ss;   // full ||k||^2 of row rbase+rf*16+c
    }
#pragma unroll
    for (int rf = 0; rf < 2; ++rf) {
      float dg[4];
#pragma unroll
      for (int r = 0; r < 4; ++r)
        dg[r] = 0.5f * DN2 * __shfl(s2[rf], (lane & 48) | (4 * g + r)) + stab;
#pragma unroll
      for (int jf = 0; jf < 4; ++jf) {
        f32x4 d = __builtin_amdgcn_mfma_f32_16x16x32_bf16(af[rf], pf[jf], z, 0, 0, 0);
        u16 b0 = f2bf(__expf(d[0] - dg[0]) + KEPS);
        u16 b1 = f2bf(__expf(d[1] - dg[1]) + KEPS);
        u16 b2 = f2bf(__expf(d[2] - dg[2]) + KEPS);
        u16 b3 = f2bf(__expf(d[3] - dg[3]) + KEPS);
        uint2 pk;
        pk.x = (u32)b0 | ((u32)b1 << 16);
        pk.y = (u32)b2 | ((u32)b3 << 16);
        *reinterpret_cast<uint2*>(&kfT[(size_t)(w * 64 + jf * 16 + c) * 40 + rf * 16 + 4 * g]) = pk;
        ksacc[jf] += bf2f(b0) + bf2f(b1) + bf2f(b2) + bf2f(b3);
      }
    }
#pragma unroll
    for (int mf = 0; mf < 4; ++mf) {
      bf16x8 a = *reinterpret_cast<const bf16x8*>(&kfT[(size_t)(w * 64 + mf * 16 + c) * 40 + g * 8]);
#pragma unroll
      for (int df = 0; df < 2; ++df) {
        bf16x8 b = *reinterpret_cast<const bf16x8*>(
            VT + (size_t)(h * DHD + df * 16 + c) * NTOK + rbase + g * 8);
        cacc[mf][df] = __builtin_amdgcn_mfma_f32_16x16x32_bf16(a, b, cacc[mf][df], 0, 0, 0);
      }
    }
  }
#pragma unroll
  for (int jf = 0; jf < 4; ++jf) {
    float vv = ksacc[jf];
    vv += __shfl_xor(vv, 16); vv += __shfl_xor(vv, 32);
    if (g == 0) pks[((size_t)h * NCHK + ch) * MF + w * 64 + jf * 16 + c] = vv;
  }
#pragma unroll
  for (int mf = 0; mf < 4; ++mf)
#pragma unroll
    for (int df = 0; df < 2; ++df)
#pragma unroll
      for (int r = 0; r < 4; ++r) {
        int m = w * 64 + mf * 16 + 4 * g + r;
        int d = df * 16 + c;
        pctx[(((size_t)h * NCHK + ch) * MF + m) * DHD + d] = cacc[mf][df][r];
      }
}

// ---------------- reduce partials -> ctxT bf16 [H][32][256] + ksum [H][256] ----------------
__global__ __launch_bounds__(256) void reduce_all(
    const float* __restrict__ pctx, const float* __restrict__ pks,
    u16* __restrict__ ctxT, float* __restrict__ ksg)
{
  int idx = blockIdx.x * 256 + threadIdx.x;
  if (idx < HN * MF * DHD) {
    int h = idx >> 13, md = idx & 8191;
    int m = md >> 5, d = md & 31;
    float s = 0.f;
    for (int c = 0; c < NCHK; ++c) s += pctx[((size_t)h * NCHK + c) * 8192 + md];
    ctxT[(size_t)h * 8192 + d * MF + m] = f2bf(s);
  } else {
    int i2 = idx - HN * MF * DHD;
    if (i2 < HN * MF) {
      int h = i2 >> 8, m = i2 & 255;
      float s = 0.f;
      for (int c = 0; c < NCHK; ++c) s += pks[((size_t)h * NCHK + c) * MF + m];
      ksg[i2] = s;
    }
  }
}

// ---------------- qf + out via MFMA (diag in-kernel) ----------------
__global__ __launch_bounds__(256) void qout_kernel(
    const u16* __restrict__ Qm, const u16* __restrict__ pjb,
    const u16* __restrict__ ctxT, const float* __restrict__ ksg,
    u16* __restrict__ Am)
{
  __shared__ __align__(16) u16 qfs[4][32 * 40];
  const int tid = threadIdx.x, lane = tid & 63, w = tid >> 6;
  const int h = blockIdx.y;
  const int n0 = blockIdx.x * 128 + w * 32;
  const int g = lane >> 4, c = lane & 15;
  const f32x4 z = (f32x4){0.f, 0.f, 0.f, 0.f};

  bf16x8 af[2];
  float s2[2];
#pragma unroll
  for (int rf = 0; rf < 2; ++rf) {
    af[rf] = *reinterpret_cast<const bf16x8*>(
        Qm + (size_t)(n0 + rf * 16 + c) * EDIM + h * DHD + g * 8);
    uint4 ui = *reinterpret_cast<const uint4*>(&af[rf]);
    u32 wd[4] = {ui.x, ui.y, ui.z, ui.w};
    float ss = 0.f;
#pragma unroll
    for (int i = 0; i < 4; ++i) {
      float a = bf2f((u16)(wd[i] & 0xffff)), b = bf2f((u16)(wd[i] >> 16));
      ss += a * a + b * b;
    }
    ss += __shfl_xor(ss, 16); ss += __shfl_xor(ss, 32);
    s2[rf] = ss;
  }

  float rmax[2][4];
#pragma unroll
  for (int rf = 0; rf < 2; ++rf)
#pragma unroll
    for (int r = 0; r < 4; ++r) rmax[rf][r] = -3.4e38f;
#pragma unroll
  for (int jf = 0; jf < 16; ++jf) {
    bf16x8 b = *reinterpret_cast<const bf16x8*>(pjb + (jf * 16 + c) * DHD + g * 8);
#pragma unroll
    for (int rf = 0; rf < 2; ++rf) {
      f32x4 d = __builtin_amdgcn_mfma_f32_16x16x32_bf16(af[rf], b, z, 0, 0, 0);
#pragma unroll
      for (int r = 0; r < 4; ++r) rmax[rf][r] = fmaxf(rmax[rf][r], d[r]);
    }
  }
#pragma unroll
  for (int rf = 0; rf < 2; ++rf)
#pragma unroll
    for (int r = 0; r < 4; ++r) {
      float vv = rmax[rf][r];
      vv = fmaxf(vv, __shfl_xor(vv, 1)); vv = fmaxf(vv, __shfl_xor(vv, 2));
      vv = fmaxf(vv, __shfl_xor(vv, 4)); vv = fmaxf(vv, __shfl_xor(vv, 8));
      rmax[rf][r] = vv;
    }
  float crow[2][4];
#pragma unroll
  for (int rf = 0; rf < 2; ++rf)
#pragma unroll
    for (int r = 0; r < 4; ++r)
      crow[rf][r] = 0.5f * DN2 * __shfl(s2[rf], (lane & 48) | (4 * g + r)) + rmax[rf][r];

  f32x4 oacc[2][2];
#pragma unroll
  for (int rf = 0; rf < 2; ++rf)
#pragma unroll
    for (int df = 0; df < 2; ++df) oacc[rf][df] = z;
  float Dacc[2][4];
#pragma unroll
  for (int rf = 0; rf < 2; ++rf)
#pragma unroll
    for (int r = 0; r < 4; ++r) Dacc[rf][r] = 0.f;

  for (int ks = 0; ks < 8; ++ks) {
#pragma unroll
    for (int jj = 0; jj < 2; ++jj) {
      const int jf = ks * 2 + jj;
      bf16x8 b = *reinterpret_cast<const bf16x8*>(pjb + (jf * 16 + c) * DHD + g * 8);
      const float ksv = ksg[h * MF + jf * 16 + c];
#pragma unroll
      for (int rf = 0; rf < 2; ++rf) {
        f32x4 d = __builtin_amdgcn_mfma_f32_16x16x32_bf16(af[rf], b, z, 0, 0, 0);
#pragma unroll
        for (int r = 0; r < 4; ++r) {
          float q = __expf(d[r] - crow[rf][r]) + KEPS;
          u16 qb_ = f2bf(q);
          qfs[w][(rf * 16 + 4 * g + r) * 40 + jj * 16 + c] = qb_;
          Dacc[rf][r] += bf2f(qb_) * ksv;
        }
      }
    }
#pragma unroll
    for (int rf = 0; rf < 2; ++rf) {
      bf16x8 a = *reinterpret_cast<const bf16x8*>(&qfs[w][(rf * 16 + c) * 40 + g * 8]);
#pragma unroll
      for (int df = 0; df < 2; ++df) {
        bf16x8 bc = *reinterpret_cast<const bf16x8*>(
            ctxT + (size_t)(h * DHD + df * 16 + c) * MF + ks * 32 + g * 8);
        oacc[rf][df] = __builtin_amdgcn_mfma_f32_16x16x32_bf16(a, bc, oacc[rf][df], 0, 0, 0);
      }
    }
  }
#pragma unroll
  for (int rf = 0; rf < 2; ++rf)
#pragma unroll
    for (int r = 0; r < 4; ++r) {
      float vv = Dacc[rf][r];
      vv += __shfl_xor(vv, 1); vv += __shfl_xor(vv, 2);
      vv += __shfl_xor(vv, 4); vv += __shfl_xor(vv, 8);
      Dacc[rf][r] = vv;
    }
#pragma unroll
  for (int rf = 0; rf < 2; ++rf)
#pragma unroll
    for (int df = 0; df < 2; ++df)
#pragma unroll
      for (int r = 0; r < 4; ++r)
        Am[(size_t)(n0 + rf * 16 + 4 * g + r) * EDIM + h * DHD + df * 16 + c] =
            f2bf(oacc[rf][df][r] / Dacc[rf][r]);
}

// ---------------- host ----------------
extern "C" void kernel_launch(void* const* d_in, const int* in_sizes, int n_in,
                              void* d_out, int out_size, void* d_ws, size_t ws_size,
                              hipStream_t stream)
{
  const float* x    = (const float*)d_in[0];
  const float* Wpin = (const float*)d_in[1];
  const float* bpin = (const float*)d_in[2];
  const float* lag  = (const float*)d_in[3];
  const float* lab  = (const float*)d_in[4];
  const float* Wq   = (const float*)d_in[5];
  const float* Wk   = (const float*)d_in[6];
  const float* Wv   = (const float*)d_in[7];
  const float* Wo   = (const float*)d_in[8];
  const float* bo   = (const float*)d_in[9];
  const float* lbg  = (const float*)d_in[10];
  const float* lbb  = (const float*)d_in[11];
  const float* Wf1  = (const float*)d_in[12];
  const float* bf1  = (const float*)d_in[13];
  const float* Wf2  = (const float*)d_in[14];
  const float* bf2  = (const float*)d_in[15];
  const float* Wpo  = (const float*)d_in[16];
  const float* bpo  = (const float*)d_in[17];
  const float* n1g  = (const float*)d_in[18];
  const float* n1b  = (const float*)d_in[19];
  const float* Wn1  = (const float*)d_in[20];
  const float* bn1  = (const float*)d_in[21];
  const float* Wn2  = (const float*)d_in[22];
  const float* bn2  = (const float*)d_in[23];
  const float* n2g  = (const float*)d_in[24];
  const float* n2b  = (const float*)d_in[25];
  const float* Wc   = (const float*)d_in[26];
  const float* bc   = (const float*)d_in[27];
  const float* proj = (const float*)d_in[28];

  size_t off = 0;
  char* base = (char*)d_ws;
  auto alloc = [&](size_t bytes) -> void* {
    void* p = base + off;
    off += (bytes + 255) & ~(size_t)255;
    return p;
  };
  u16* hb  = (u16*)alloc((size_t)NTOK * EDIM * 2);
  u16* yb  = (u16*)alloc((size_t)NTOK * EDIM * 2);
  u16* qb  = (u16*)alloc((size_t)NTOK * EDIM * 2);
  u16* kb  = (u16*)alloc((size_t)NTOK * EDIM * 2);
  u16* vb  = (u16*)alloc((size_t)NTOK * EDIM * 2);
  u16* hid = (u16*)alloc((size_t)NTOK * FDIM * 2);
  u16* VT  = (u16*)alloc((size_t)HN * DHD * NTOK * 2);
  u16* pjb = (u16*)alloc((size_t)LLAYERS * MF * DHD * 2);
  u16* ctxT = (u16*)alloc((size_t)HN * DHD * MF * 2);
  float* ksg  = (float*)alloc((size_t)HN * MF * 4);
  float* pctx = (float*)alloc((size_t)HN * NCHK * MF * DHD * 4);
  float* pks  = (float*)alloc((size_t)HN * NCHK * MF * 4);
  unsigned* stabp = (unsigned*)alloc(256);
  u16* wts = (u16*)alloc((size_t)753664 * 2);

  // wts layout (grouped by array, per prep_kernel)
  u16* Wpint = wts;
  auto Wqt  = [&](int l){ return wts +  65536 + (size_t)l * 16384; };
  auto Wkt  = [&](int l){ return wts +  98304 + (size_t)l * 16384; };
  auto Wvt  = [&](int l){ return wts + 131072 + (size_t)l * 16384; };
  auto Wot  = [&](int l){ return wts + 163840 + (size_t)l * 16384; };
  auto Wpot = [&](int l){ return wts + 196608 + (size_t)l * 16384; };
  auto Wf1t = [&](int l){ return wts + 229376 + (size_t)l * 65536; };
  auto Wf2t = [&](int l){ return wts + 360448 + (size_t)l * 65536; };
  auto Wn1t = [&](int l){ return wts + 491520 + (size_t)l * 65536; };
  auto Wn2t = [&](int l){ return wts + 622592 + (size_t)l * 65536; };

  PrepArgs pa{Wpin, Wq, Wk, Wv, Wo, Wpo, Wf1, Wf2, Wn1, Wn2, proj};
  prep_kernel<<<3008, 256, 0, stream>>>(pa, wts, pjb, stabp);

  auto gemmP = [&](const u16* A, const u16* Bt, const float* bias,
                   const u16* res, u16* C, int K, int J, int op) {
    dim3 grid(NTOK / 128, J / 128);
    gemm_f<0, false><<<grid, 256, 0, stream>>>(A, nullptr, Bt, bias, res, C, K, J, op,
        nullptr, nullptr, nullptr, nullptr, nullptr, nullptr, nullptr, nullptr, nullptr);
  };

  // input: h = x@Wpin + bpin (raw -> hb), y = LN_lag0(h) -> yb
  gemm_f<1, true><<<dim3(NTOK / 128, 1), 256, 0, stream>>>(
      nullptr, x, Wpint, bpin, nullptr, hb, INDIM, EDIM, 0,
      lag, lab, yb, nullptr, nullptr, nullptr, nullptr, nullptr, nullptr);

  for (int l = 0; l < LLAYERS; ++l) {
    const u16* pjl = pjb + (size_t)l * MF * DHD;

    gemmP(yb, Wqt(l), nullptr, nullptr, qb, EDIM, EDIM, 0);
    gemmP(yb, Wkt(l), nullptr, nullptr, kb, EDIM, EDIM, 0);
    gemmP(yb, Wvt(l), nullptr, nullptr, vb, EDIM, EDIM, 0);

    vt_kernel<<<dim3(NTOK / 64, HN), 256, 0, stream>>>(vb, VT);
    smax_kernel<<<dim3(NTOK / 256, HN), 256, 0, stream>>>(kb, pjl, stabp + l);
    ctxk_kernel<<<dim3(NCHK, HN), 256, 0, stream>>>(kb, VT, pjl, stabp + l, pctx, pks);
    reduce_all<<<132, 256, 0, stream>>>(pctx, pks, ctxT, ksg);
    qout_kernel<<<dim3(NTOK / 128, HN), 256, 0, stream>>>(qb, pjl, ctxT, ksg, yb);

    // h1 = h + a@Wo + bo (raw -> qb), y2 = LN_lb(h1) -> kb
    gemm_f<1, false><<<dim3(NTOK / 128, 1), 256, 0, stream>>>(
        yb, nullptr, Wot(l), bo + l * EDIM, hb, qb, EDIM, EDIM, 0,
        lbg + l * EDIM, lbb + l * EDIM, kb, nullptr, nullptr, nullptr,
        nullptr, nullptr, nullptr);
    // hid = gelu(y2@Wf1 + bf1)
    gemmP(kb, Wf1t(l), bf1 + l * FDIM, nullptr, hid, EDIM, FDIM, 1);
    // h2 = h1 + hid@Wf2 + bf2 (raw -> vb)
    gemmP(hid, Wf2t(l), bf2 + l * EDIM, qb, vb, FDIM, EDIM, 0);
    // h = LN_n1(h + h2@Wpo + bpo) -> hb
    gemm_f<1, false><<<dim3(NTOK / 128, 1), 256, 0, stream>>>(
        vb, nullptr, Wpot(l), bpo + l * EDIM, hb, nullptr, EDIM, EDIM, 0,
        n1g + l * EDIM, n1b + l * EDIM, hb, nullptr, nullptr, nullptr,
        nullptr, nullptr, nullptr);
    // hid = relu(h@Wn1 + bn1)
    gemmP(hb, Wn1t(l), bn1 + l * FDIM, nullptr, hid, EDIM, FDIM, 2);
    // h = LN_n2(h + hid@Wn2 + bn2); l<last: y_next = LN_lag(h); last: cls
    if (l < LLAYERS - 1) {
      gemm_f<2, false><<<dim3(NTOK / 128, 1), 256, 0, stream>>>(
          hid, nullptr, Wn2t(l), bn2 + l * EDIM, hb, nullptr, FDIM, EDIM, 0,
          n2g + l * EDIM, n2b + l * EDIM, hb,
          lag + (l + 1) * EDIM, lab + (l + 1) * EDIM, yb,
          nullptr, nullptr, nullptr);
    } else {
      gemm_f<3, false><<<dim3(NTOK / 128, 1), 256, 0, stream>>>(
          hid, nullptr, Wn2t(l), bn2 + l * EDIM, hb, nullptr, FDIM, EDIM, 0,
          n2g + l * EDIM, n2b + l * EDIM, nullptr, nullptr, nullptr, nullptr,
          Wc, bc, (float*)d_out);
    }
  }
}